// Round 1
// baseline (4823.537 us; speedup 1.0000x reference)
//
#include <hip/hip_runtime.h>
#include <math.h>

#define BB 2
#define TT 1024
#define DD 1024
#define HH 16
#define HS 64
#define NROWS (BB*TT)   // 2048

constexpr float EPS   = 1e-5f;
constexpr float SCALE = 8.0f;   // faithful bug: scores * sqrt(HS)

// ---------------- RMSNorm: one block per row, 256 threads, D=1024 ----------------
__global__ __launch_bounds__(256) void rmsnorm_kernel(const float* __restrict__ x,
                                                      const float* __restrict__ w,
                                                      float* __restrict__ out) {
    const int row = blockIdx.x;
    const int tid = threadIdx.x;
    const float* xr = x + (size_t)row * DD;
    float* yr = out + (size_t)row * DD;

    float4 xv = reinterpret_cast<const float4*>(xr)[tid];   // 256*4 = 1024
    float ss = xv.x*xv.x + xv.y*xv.y + xv.z*xv.z + xv.w*xv.w;

    __shared__ float red[256];
    red[tid] = ss; __syncthreads();
    for (int s = 128; s > 0; s >>= 1) {
        if (tid < s) red[tid] += red[tid + s];
        __syncthreads();
    }
    const float inv = rsqrtf(red[0] * (1.0f / DD) + EPS);

    float4 wv = reinterpret_cast<const float4*>(w)[tid];
    float4 o;
    o.x = xv.x * inv * wv.x;
    o.y = xv.y * inv * wv.y;
    o.z = xv.z * inv * wv.z;
    o.w = xv.w * inv * wv.w;
    reinterpret_cast<float4*>(yr)[tid] = o;
}

// ---------------- Generic tiled fp32 GEMM: C[M,N] = A[M,K] @ B[K,N] ----------------
// EPI: 0 = none, 1 = +bias, 2 = +bias then exact GELU, 3 = +bias then +residual
// HEADB:  B weight is (H, D, HS) gathered as W[k, n] = w[(n/HS)*D*HS + k*HS + (n%HS)]
//         (requires 64-wide n-tiles aligned to head boundary; HS==64 guarantees this)
// HEADOUT: store to [B, H, T, HS] layout instead of [M, N]
template<int EPI, bool HEADB, bool HEADOUT>
__global__ __launch_bounds__(256) void gemm64(const float* __restrict__ A,
                                              const float* __restrict__ Bw,
                                              const float* __restrict__ bias,
                                              const float* __restrict__ resid,
                                              float* __restrict__ Cout,
                                              int N, int K) {
    __shared__ float As[16][65];
    __shared__ float Bs[16][65];

    const int tid = threadIdx.x;       // 256 threads
    const int tx  = tid & 15;
    const int ty  = tid >> 4;
    const int m0  = blockIdx.y * 64;
    const int n0  = blockIdx.x * 64;

    float acc[4][4] = {};

    const int la_row = tid >> 2;         // 0..63
    const int la_k   = (tid & 3) * 4;    // 0,4,8,12
    const int lb_k   = tid >> 4;         // 0..15
    const int lb_n   = (tid & 15) * 4;   // 0..60

    for (int k0 = 0; k0 < K; k0 += 16) {
        // A tile (coalesced float4 rows)
        float4 av = *reinterpret_cast<const float4*>(&A[(size_t)(m0 + la_row) * K + k0 + la_k]);
        As[la_k + 0][la_row] = av.x;
        As[la_k + 1][la_row] = av.y;
        As[la_k + 2][la_row] = av.z;
        As[la_k + 3][la_row] = av.w;

        // B tile
        const float* bp;
        if (HEADB) {
            // n-tile covers exactly one head (n0 % 64 == 0, HS == 64)
            bp = &Bw[(size_t)(n0 >> 6) * DD * HS + (size_t)(k0 + lb_k) * HS + lb_n];
        } else {
            bp = &Bw[(size_t)(k0 + lb_k) * N + n0 + lb_n];
        }
        float4 bv = *reinterpret_cast<const float4*>(bp);
        Bs[lb_k][lb_n + 0] = bv.x;
        Bs[lb_k][lb_n + 1] = bv.y;
        Bs[lb_k][lb_n + 2] = bv.z;
        Bs[lb_k][lb_n + 3] = bv.w;

        __syncthreads();
        #pragma unroll
        for (int kk = 0; kk < 16; ++kk) {
            float a[4], b[4];
            #pragma unroll
            for (int i = 0; i < 4; ++i) a[i] = As[kk][ty * 4 + i];
            #pragma unroll
            for (int j = 0; j < 4; ++j) b[j] = Bs[kk][tx * 4 + j];
            #pragma unroll
            for (int i = 0; i < 4; ++i)
                #pragma unroll
                for (int j = 0; j < 4; ++j)
                    acc[i][j] = fmaf(a[i], b[j], acc[i][j]);
        }
        __syncthreads();
    }

    #pragma unroll
    for (int i = 0; i < 4; ++i) {
        const int m = m0 + ty * 4 + i;
        #pragma unroll
        for (int j = 0; j < 4; ++j) {
            const int n = n0 + tx * 4 + j;
            float v = acc[i][j];
            if (EPI >= 1) v += bias[n];
            if (EPI == 2) v = 0.5f * v * (1.0f + erff(v * 0.70710678118f)); // exact GELU
            if (EPI == 3) v += resid[(size_t)m * N + n];
            size_t oidx;
            if (HEADOUT) {
                const int b = m >> 10, t = m & (TT - 1);  // T = 1024
                const int h = n >> 6, e = n & (HS - 1);
                oidx = ((size_t)(b * HH + h) * TT + t) * HS + e;
            } else {
                oidx = (size_t)m * N + n;
            }
            Cout[oidx] = v;
        }
    }
}

// ---------------- Attention: one block per (b,h,t) query row ----------------
// Q,K,V in [B,H,T,HS]; output stored concat-heads [B,T,D].
template<bool CAUSAL>
__global__ __launch_bounds__(256) void attn_kernel(const float* __restrict__ Q,
                                                   const float* __restrict__ Km,
                                                   const float* __restrict__ Vm,
                                                   float* __restrict__ O) {
    const int t   = blockIdx.x;
    const int bh  = blockIdx.y;          // 0..B*H-1
    const int tid = threadIdx.x;         // 256
    const int lane = tid & 63;
    const int wave = tid >> 6;
    const int len = CAUSAL ? (t + 1) : TT;

    const float* qp = Q  + ((size_t)bh * TT + t) * HS;
    const float* kp = Km + (size_t)bh * TT * HS;
    const float* vp = Vm + (size_t)bh * TT * HS;

    __shared__ float qs[HS];
    __shared__ float p[TT];
    __shared__ float red[256];
    __shared__ float opart[4][HS];

    if (tid < HS) qs[tid] = qp[tid];
    __syncthreads();

    // scores
    float lmax = -1e30f;
    for (int s = tid; s < len; s += 256) {
        const float* kr = kp + (size_t)s * HS;
        float dot = 0.f;
        #pragma unroll
        for (int e = 0; e < HS; e += 4) {
            float4 kv = *reinterpret_cast<const float4*>(kr + e);
            dot = fmaf(qs[e + 0], kv.x, dot);
            dot = fmaf(qs[e + 1], kv.y, dot);
            dot = fmaf(qs[e + 2], kv.z, dot);
            dot = fmaf(qs[e + 3], kv.w, dot);
        }
        dot *= SCALE;
        p[s] = dot;
        lmax = fmaxf(lmax, dot);
    }
    red[tid] = lmax; __syncthreads();
    for (int s2 = 128; s2 > 0; s2 >>= 1) {
        if (tid < s2) red[tid] = fmaxf(red[tid], red[tid + s2]);
        __syncthreads();
    }
    const float mx = red[0];
    __syncthreads();

    // exp + sum
    float lsum = 0.f;
    for (int s = tid; s < len; s += 256) {
        float e = __expf(p[s] - mx);
        p[s] = e;
        lsum += e;
    }
    red[tid] = lsum; __syncthreads();
    for (int s2 = 128; s2 > 0; s2 >>= 1) {
        if (tid < s2) red[tid] += red[tid + s2];
        __syncthreads();
    }
    const float denom = red[0];
    __syncthreads();

    // PV: each wave walks an s-strided chunk, lane = e (coalesced V rows)
    float o = 0.f;
    for (int s = wave; s < len; s += 4)
        o = fmaf(p[s], vp[(size_t)s * HS + lane], o);
    opart[wave][lane] = o;
    __syncthreads();

    if (tid < HS) {
        float sum = opart[0][tid] + opart[1][tid] + opart[2][tid] + opart[3][tid];
        const int b = bh >> 4, h = bh & (HH - 1);
        O[((size_t)(b * TT + t)) * DD + h * HS + tid] = sum / denom;
    }
}

extern "C" void kernel_launch(void* const* d_in, const int* in_sizes, int n_in,
                              void* d_out, int out_size, void* d_ws, size_t ws_size,
                              hipStream_t stream) {
    const float* src      = (const float*)d_in[0];
    const float* att      = (const float*)d_in[1];
    const float* wq_m     = (const float*)d_in[2];
    const float* wk_m     = (const float*)d_in[3];
    const float* wv_m     = (const float*)d_in[4];
    const float* proj_m_w = (const float*)d_in[5];
    const float* proj_m_b = (const float*)d_in[6];
    const float* wq_f     = (const float*)d_in[7];
    const float* wk_f     = (const float*)d_in[8];
    const float* wv_f     = (const float*)d_in[9];
    const float* bq_f     = (const float*)d_in[10];
    const float* bk_f     = (const float*)d_in[11];
    const float* bv_f     = (const float*)d_in[12];
    const float* proj_f_w = (const float*)d_in[13];
    const float* proj_f_b = (const float*)d_in[14];
    const float* w1       = (const float*)d_in[15];
    const float* b1       = (const float*)d_in[16];
    const float* w2       = (const float*)d_in[17];
    const float* b2       = (const float*)d_in[18];
    const float* norm_w   = (const float*)d_in[19];
    float* out = (float*)d_out;

    float* ws = (float*)d_ws;
    const size_t M2 = (size_t)NROWS * DD;     // 2M floats
    float* xn    = ws;               // 2M (reused for all three rmsnorm sites)
    float* q     = ws + 2  * M2 / 2; // offsets in floats: keep it explicit below
    // explicit offsets (floats):
    xn           = ws + 0;
    q            = ws + 1 * M2;
    float* k     = ws + 2 * M2;
    float* v     = ws + 3 * M2;
    float* ao    = ws + 4 * M2;
    float* m_out = ws + 5 * M2;
    float* f_out = ws + 6 * M2;
    float* h1    = ws + 7 * M2;      // 8M floats (2048 x 4096)

    const dim3 blk(256);
    const dim3 gRN(NROWS);
    const dim3 gG_D(DD / 64, NROWS / 64);      // (16, 32)
    const dim3 gG_4D(4 * DD / 64, NROWS / 64); // (64, 32)
    const dim3 gAT(TT, BB * HH);               // (1024, 32)

    // ---- masked self-attention block ----
    rmsnorm_kernel<<<gRN, blk, 0, stream>>>(src, norm_w, xn);
    gemm64<0, true,  true ><<<gG_D, blk, 0, stream>>>(xn, wq_m, nullptr, nullptr, q, DD, DD);
    gemm64<0, true,  true ><<<gG_D, blk, 0, stream>>>(xn, wk_m, nullptr, nullptr, k, DD, DD);
    gemm64<0, true,  true ><<<gG_D, blk, 0, stream>>>(xn, wv_m, nullptr, nullptr, v, DD, DD);
    attn_kernel<true><<<gAT, blk, 0, stream>>>(q, k, v, ao);
    gemm64<3, false, false><<<gG_D, blk, 0, stream>>>(ao, proj_m_w, proj_m_b, src, m_out, DD, DD);

    // ---- cross attention block: q/k from rmsnorm(att), v from m_out ----
    rmsnorm_kernel<<<gRN, blk, 0, stream>>>(att, norm_w, xn);
    gemm64<1, true,  true ><<<gG_D, blk, 0, stream>>>(xn,    wq_f, bq_f, nullptr, q, DD, DD);
    gemm64<1, true,  true ><<<gG_D, blk, 0, stream>>>(xn,    wk_f, bk_f, nullptr, k, DD, DD);
    gemm64<1, true,  true ><<<gG_D, blk, 0, stream>>>(m_out, wv_f, bv_f, nullptr, v, DD, DD);
    attn_kernel<false><<<gAT, blk, 0, stream>>>(q, k, v, ao);
    gemm64<3, false, false><<<gG_D, blk, 0, stream>>>(ao, proj_f_w, proj_f_b, m_out, f_out, DD, DD);

    // ---- FFN block ----
    rmsnorm_kernel<<<gRN, blk, 0, stream>>>(f_out, norm_w, xn);
    gemm64<2, false, false><<<gG_4D, blk, 0, stream>>>(xn, w1, b1, nullptr, h1, 4 * DD, DD);
    gemm64<3, false, false><<<gG_D,  blk, 0, stream>>>(h1, w2, b2, f_out, out, DD, 4 * DD);
}

// Round 2
// 1786.181 us; speedup vs baseline: 2.7005x; 2.7005x over previous
//
#include <hip/hip_runtime.h>
#include <math.h>

#define BB 2
#define TT 1024
#define DD 1024
#define HH 16
#define HS 64
#define NROWS (BB*TT)   // 2048

constexpr float EPS   = 1e-5f;
constexpr float SCALE = 8.0f;   // faithful bug: scores * sqrt(HS)

// ---------------- RMSNorm: one block per row, 256 threads, D=1024 ----------------
__global__ __launch_bounds__(256) void rmsnorm_kernel(const float* __restrict__ x,
                                                      const float* __restrict__ w,
                                                      float* __restrict__ out) {
    const int row = blockIdx.x;
    const int tid = threadIdx.x;
    const float* xr = x + (size_t)row * DD;
    float* yr = out + (size_t)row * DD;

    float4 xv = reinterpret_cast<const float4*>(xr)[tid];   // 256*4 = 1024
    float ss = xv.x*xv.x + xv.y*xv.y + xv.z*xv.z + xv.w*xv.w;

    __shared__ float red[256];
    red[tid] = ss; __syncthreads();
    for (int s = 128; s > 0; s >>= 1) {
        if (tid < s) red[tid] += red[tid + s];
        __syncthreads();
    }
    const float inv = rsqrtf(red[0] * (1.0f / DD) + EPS);

    float4 wv = reinterpret_cast<const float4*>(w)[tid];
    float4 o;
    o.x = xv.x * inv * wv.x;
    o.y = xv.y * inv * wv.y;
    o.z = xv.z * inv * wv.z;
    o.w = xv.w * inv * wv.w;
    reinterpret_cast<float4*>(yr)[tid] = o;
}

// ---------------- Generic tiled fp32 GEMM: C[M,N] = A[M,K] @ B[K,N] ----------------
// EPI: 0 = none, 1 = +bias, 2 = +bias then exact GELU, 3 = +bias then +residual
// HEADB:  B weight is (H, D, HS) gathered as W[k, n] = w[(n/HS)*D*HS + k*HS + (n%HS)]
// HEADOUT: store to [B, H, T, HS] layout instead of [M, N]
template<int EPI, bool HEADB, bool HEADOUT>
__global__ __launch_bounds__(256) void gemm64(const float* __restrict__ A,
                                              const float* __restrict__ Bw,
                                              const float* __restrict__ bias,
                                              const float* __restrict__ resid,
                                              float* __restrict__ Cout,
                                              int N, int K) {
    __shared__ float As[16][65];
    __shared__ float Bs[16][65];

    const int tid = threadIdx.x;       // 256 threads
    const int tx  = tid & 15;
    const int ty  = tid >> 4;
    const int m0  = blockIdx.y * 64;
    const int n0  = blockIdx.x * 64;

    float acc[4][4] = {};

    const int la_row = tid >> 2;         // 0..63
    const int la_k   = (tid & 3) * 4;    // 0,4,8,12
    const int lb_k   = tid >> 4;         // 0..15
    const int lb_n   = (tid & 15) * 4;   // 0..60

    for (int k0 = 0; k0 < K; k0 += 16) {
        float4 av = *reinterpret_cast<const float4*>(&A[(size_t)(m0 + la_row) * K + k0 + la_k]);
        As[la_k + 0][la_row] = av.x;
        As[la_k + 1][la_row] = av.y;
        As[la_k + 2][la_row] = av.z;
        As[la_k + 3][la_row] = av.w;

        const float* bp;
        if (HEADB) {
            bp = &Bw[(size_t)(n0 >> 6) * DD * HS + (size_t)(k0 + lb_k) * HS + lb_n];
        } else {
            bp = &Bw[(size_t)(k0 + lb_k) * N + n0 + lb_n];
        }
        float4 bv = *reinterpret_cast<const float4*>(bp);
        Bs[lb_k][lb_n + 0] = bv.x;
        Bs[lb_k][lb_n + 1] = bv.y;
        Bs[lb_k][lb_n + 2] = bv.z;
        Bs[lb_k][lb_n + 3] = bv.w;

        __syncthreads();
        #pragma unroll
        for (int kk = 0; kk < 16; ++kk) {
            float a[4], b[4];
            #pragma unroll
            for (int i = 0; i < 4; ++i) a[i] = As[kk][ty * 4 + i];
            #pragma unroll
            for (int j = 0; j < 4; ++j) b[j] = Bs[kk][tx * 4 + j];
            #pragma unroll
            for (int i = 0; i < 4; ++i)
                #pragma unroll
                for (int j = 0; j < 4; ++j)
                    acc[i][j] = fmaf(a[i], b[j], acc[i][j]);
        }
        __syncthreads();
    }

    #pragma unroll
    for (int i = 0; i < 4; ++i) {
        const int m = m0 + ty * 4 + i;
        #pragma unroll
        for (int j = 0; j < 4; ++j) {
            const int n = n0 + tx * 4 + j;
            float v = acc[i][j];
            if (EPI >= 1) v += bias[n];
            if (EPI == 2) v = 0.5f * v * (1.0f + erff(v * 0.70710678118f)); // exact GELU
            if (EPI == 3) v += resid[(size_t)m * N + n];
            size_t oidx;
            if (HEADOUT) {
                const int b = m >> 10, t = m & (TT - 1);
                const int h = n >> 6, e = n & (HS - 1);
                oidx = ((size_t)(b * HH + h) * TT + t) * HS + e;
            } else {
                oidx = (size_t)m * N + n;
            }
            Cout[oidx] = v;
        }
    }
}

// ---------------- Tiled flash attention (fp32, register-blocked) ----------------
// grid: (T/64, B*H); block: 256 threads as 16x16; each thread owns 4x4 of the
// 64(q) x 64(s) score tile and 4x4 of the 64(q) x 64(e) output accumulator.
// Q,K,V in [B,H,T,HS]; output written concat-heads [B,T,D].
template<bool CAUSAL>
__global__ __launch_bounds__(256) void attn_tile(const float* __restrict__ Q,
                                                 const float* __restrict__ Km,
                                                 const float* __restrict__ Vm,
                                                 float* __restrict__ O) {
    const int iq  = blockIdx.x;          // q-tile index
    const int bh  = blockIdx.y;          // 0..B*H-1
    const int tid = threadIdx.x;
    const int tx  = tid & 15;
    const int ty  = tid >> 4;

    __shared__ float Qs[HS][68];   // Q^T: Qs[e][q]   (pre-scaled by SCALE)
    __shared__ float Ks[HS][68];   // K^T: Ks[e][s]
    __shared__ float Vs[64][68];   // V:   Vs[s][e]
    __shared__ float Ps[64][68];   // P^T: Ps[s][q]

    const float* qbase = Q  + ((size_t)bh * TT + (size_t)iq * 64) * HS;
    const float* kbase = Km + (size_t)bh * TT * HS;
    const float* vbase = Vm + (size_t)bh * TT * HS;

    // load Q tile transposed, pre-scaled
    #pragma unroll
    for (int r = 0; r < 4; ++r) {
        int idx = tid + r * 256;        // 0..1023
        int row = idx >> 4;             // q 0..63
        int e0  = (idx & 15) * 4;
        float4 qv = *reinterpret_cast<const float4*>(qbase + (size_t)row * HS + e0);
        Qs[e0 + 0][row] = qv.x * SCALE;
        Qs[e0 + 1][row] = qv.y * SCALE;
        Qs[e0 + 2][row] = qv.z * SCALE;
        Qs[e0 + 3][row] = qv.w * SCALE;
    }

    float o_acc[4][4] = {};
    float m_run[4], l_run[4];
    #pragma unroll
    for (int i = 0; i < 4; ++i) { m_run[i] = -1e30f; l_run[i] = 0.f; }

    const int ntiles = CAUSAL ? (iq + 1) : (TT / 64);
    for (int js = 0; js < ntiles; ++js) {
        __syncthreads();   // previous iteration done with Ks/Vs/Ps
        // load K tile (transposed) + V tile (natural)
        #pragma unroll
        for (int r = 0; r < 4; ++r) {
            int idx = tid + r * 256;
            int row = idx >> 4;          // s 0..63
            int e0  = (idx & 15) * 4;
            const size_t g = (size_t)(js * 64 + row) * HS + e0;
            float4 kv = *reinterpret_cast<const float4*>(kbase + g);
            Ks[e0 + 0][row] = kv.x;
            Ks[e0 + 1][row] = kv.y;
            Ks[e0 + 2][row] = kv.z;
            Ks[e0 + 3][row] = kv.w;
            float4 vv = *reinterpret_cast<const float4*>(vbase + g);
            *reinterpret_cast<float4*>(&Vs[row][e0]) = vv;
        }
        __syncthreads();

        // S = (SCALE*Q) . K^T  — register blocked
        float sacc[4][4] = {};
        #pragma unroll 8
        for (int e = 0; e < HS; ++e) {
            float4 a = *reinterpret_cast<const float4*>(&Qs[e][ty * 4]);
            float4 b = *reinterpret_cast<const float4*>(&Ks[e][tx * 4]);
            float av[4] = {a.x, a.y, a.z, a.w};
            float bv[4] = {b.x, b.y, b.z, b.w};
            #pragma unroll
            for (int i = 0; i < 4; ++i)
                #pragma unroll
                for (int j = 0; j < 4; ++j)
                    sacc[i][j] = fmaf(av[i], bv[j], sacc[i][j]);
        }

        // causal mask on the diagonal tile
        if (CAUSAL && js == iq) {
            #pragma unroll
            for (int i = 0; i < 4; ++i) {
                const int q = ty * 4 + i;
                #pragma unroll
                for (int j = 0; j < 4; ++j) {
                    const int s = tx * 4 + j;
                    if (s > q) sacc[i][j] = -1e30f;
                }
            }
        }

        // online softmax (row groups = 16 consecutive lanes, shfl_xor reduce)
        float rs[4];
        #pragma unroll
        for (int i = 0; i < 4; ++i) {
            float rm = fmaxf(fmaxf(sacc[i][0], sacc[i][1]), fmaxf(sacc[i][2], sacc[i][3]));
            #pragma unroll
            for (int d = 1; d < 16; d <<= 1)
                rm = fmaxf(rm, __shfl_xor(rm, d));
            const float mnew = fmaxf(m_run[i], rm);
            const float corr = __expf(m_run[i] - mnew);
            float sum = 0.f;
            #pragma unroll
            for (int j = 0; j < 4; ++j) {
                const float p = __expf(sacc[i][j] - mnew);
                Ps[tx * 4 + j][ty * 4 + i] = p;
                sum += p;
            }
            #pragma unroll
            for (int d = 1; d < 16; d <<= 1)
                sum += __shfl_xor(sum, d);
            l_run[i] = l_run[i] * corr + sum;
            m_run[i] = mnew;
            #pragma unroll
            for (int j = 0; j < 4; ++j) o_acc[i][j] *= corr;
            rs[i] = sum; (void)rs;
        }
        __syncthreads();   // Ps visible

        // O += P . V — register blocked
        #pragma unroll 8
        for (int s = 0; s < 64; ++s) {
            float4 a = *reinterpret_cast<const float4*>(&Ps[s][ty * 4]);
            float4 b = *reinterpret_cast<const float4*>(&Vs[s][tx * 4]);
            float av[4] = {a.x, a.y, a.z, a.w};
            float bv[4] = {b.x, b.y, b.z, b.w};
            #pragma unroll
            for (int i = 0; i < 4; ++i)
                #pragma unroll
                for (int j = 0; j < 4; ++j)
                    o_acc[i][j] = fmaf(av[i], bv[j], o_acc[i][j]);
        }
    }

    // epilogue: normalize and store concat-heads [B,T,D]
    const int b = bh >> 4, h = bh & (HH - 1);
    #pragma unroll
    for (int i = 0; i < 4; ++i) {
        const float inv = 1.0f / l_run[i];
        const int t = iq * 64 + ty * 4 + i;
        float4 ov;
        ov.x = o_acc[i][0] * inv;
        ov.y = o_acc[i][1] * inv;
        ov.z = o_acc[i][2] * inv;
        ov.w = o_acc[i][3] * inv;
        *reinterpret_cast<float4*>(&O[((size_t)(b * TT + t)) * DD + h * HS + tx * 4]) = ov;
    }
}

extern "C" void kernel_launch(void* const* d_in, const int* in_sizes, int n_in,
                              void* d_out, int out_size, void* d_ws, size_t ws_size,
                              hipStream_t stream) {
    const float* src      = (const float*)d_in[0];
    const float* att      = (const float*)d_in[1];
    const float* wq_m     = (const float*)d_in[2];
    const float* wk_m     = (const float*)d_in[3];
    const float* wv_m     = (const float*)d_in[4];
    const float* proj_m_w = (const float*)d_in[5];
    const float* proj_m_b = (const float*)d_in[6];
    const float* wq_f     = (const float*)d_in[7];
    const float* wk_f     = (const float*)d_in[8];
    const float* wv_f     = (const float*)d_in[9];
    const float* bq_f     = (const float*)d_in[10];
    const float* bk_f     = (const float*)d_in[11];
    const float* bv_f     = (const float*)d_in[12];
    const float* proj_f_w = (const float*)d_in[13];
    const float* proj_f_b = (const float*)d_in[14];
    const float* w1       = (const float*)d_in[15];
    const float* b1       = (const float*)d_in[16];
    const float* w2       = (const float*)d_in[17];
    const float* b2       = (const float*)d_in[18];
    const float* norm_w   = (const float*)d_in[19];
    float* out = (float*)d_out;

    float* ws = (float*)d_ws;
    const size_t M2 = (size_t)NROWS * DD;     // 2M floats
    float* xn    = ws + 0 * M2;
    float* q     = ws + 1 * M2;
    float* k     = ws + 2 * M2;
    float* v     = ws + 3 * M2;
    float* ao    = ws + 4 * M2;
    float* m_out = ws + 5 * M2;
    float* f_out = ws + 6 * M2;
    float* h1    = ws + 7 * M2;      // 2048 x 4096

    const dim3 blk(256);
    const dim3 gRN(NROWS);
    const dim3 gG_D(DD / 64, NROWS / 64);      // (16, 32)
    const dim3 gG_4D(4 * DD / 64, NROWS / 64); // (64, 32)
    const dim3 gAT(TT / 64, BB * HH);          // (16, 32)

    // ---- masked self-attention block ----
    rmsnorm_kernel<<<gRN, blk, 0, stream>>>(src, norm_w, xn);
    gemm64<0, true,  true ><<<gG_D, blk, 0, stream>>>(xn, wq_m, nullptr, nullptr, q, DD, DD);
    gemm64<0, true,  true ><<<gG_D, blk, 0, stream>>>(xn, wk_m, nullptr, nullptr, k, DD, DD);
    gemm64<0, true,  true ><<<gG_D, blk, 0, stream>>>(xn, wv_m, nullptr, nullptr, v, DD, DD);
    attn_tile<true><<<gAT, blk, 0, stream>>>(q, k, v, ao);
    gemm64<3, false, false><<<gG_D, blk, 0, stream>>>(ao, proj_m_w, proj_m_b, src, m_out, DD, DD);

    // ---- cross attention block: q/k from rmsnorm(att), v from m_out ----
    rmsnorm_kernel<<<gRN, blk, 0, stream>>>(att, norm_w, xn);
    gemm64<1, true,  true ><<<gG_D, blk, 0, stream>>>(xn,    wq_f, bq_f, nullptr, q, DD, DD);
    gemm64<1, true,  true ><<<gG_D, blk, 0, stream>>>(xn,    wk_f, bk_f, nullptr, k, DD, DD);
    gemm64<1, true,  true ><<<gG_D, blk, 0, stream>>>(m_out, wv_f, bv_f, nullptr, v, DD, DD);
    attn_tile<false><<<gAT, blk, 0, stream>>>(q, k, v, ao);
    gemm64<3, false, false><<<gG_D, blk, 0, stream>>>(ao, proj_f_w, proj_f_b, m_out, f_out, DD, DD);

    // ---- FFN block ----
    rmsnorm_kernel<<<gRN, blk, 0, stream>>>(f_out, norm_w, xn);
    gemm64<2, false, false><<<gG_4D, blk, 0, stream>>>(xn, w1, b1, nullptr, h1, 4 * DD, DD);
    gemm64<3, false, false><<<gG_D,  blk, 0, stream>>>(h1, w2, b2, f_out, out, DD, 4 * DD);
}

// Round 3
// 595.723 us; speedup vs baseline: 8.0969x; 2.9983x over previous
//
#include <hip/hip_runtime.h>
#include <math.h>

#define BB 2
#define TT 1024
#define DD 1024
#define HH 16
#define HS 64
#define NROWS (BB*TT)   // 2048

typedef __attribute__((ext_vector_type(8))) short bf16x8;
typedef __attribute__((ext_vector_type(4))) float f32x4;

constexpr float EPS   = 1e-5f;
constexpr float SCALE = 8.0f;   // faithful bug: scores * sqrt(HS)

__device__ __forceinline__ unsigned short f2bf(float f) {
    unsigned u = __float_as_uint(f);
    u += 0x7FFFu + ((u >> 16) & 1u);          // round-to-nearest-even
    return (unsigned short)(u >> 16);
}
__device__ __forceinline__ float bflo(unsigned u) { return __uint_as_float(u << 16); }
__device__ __forceinline__ float bfhi(unsigned u) { return __uint_as_float(u & 0xFFFF0000u); }

__device__ __forceinline__ void load_lds16(const unsigned short* g, unsigned short* l) {
    __builtin_amdgcn_global_load_lds(
        (const __attribute__((address_space(1))) unsigned int*)g,
        (__attribute__((address_space(3))) unsigned int*)l, 16, 0, 0);
}

// ---------------- RMSNorm: fp32 in -> bf16 out ----------------
__global__ __launch_bounds__(256) void rmsnorm_kernel(const float* __restrict__ x,
                                                      const float* __restrict__ w,
                                                      unsigned short* __restrict__ out) {
    const int row = blockIdx.x;
    const int tid = threadIdx.x;
    const float* xr = x + (size_t)row * DD;

    float4 xv = reinterpret_cast<const float4*>(xr)[tid];
    float ss = xv.x*xv.x + xv.y*xv.y + xv.z*xv.z + xv.w*xv.w;

    __shared__ float red[256];
    red[tid] = ss; __syncthreads();
    for (int s = 128; s > 0; s >>= 1) {
        if (tid < s) red[tid] += red[tid + s];
        __syncthreads();
    }
    const float inv = rsqrtf(red[0] * (1.0f / DD) + EPS);

    float4 wv = reinterpret_cast<const float4*>(w)[tid];
    ushort4 o;
    o.x = f2bf(xv.x * inv * wv.x);
    o.y = f2bf(xv.y * inv * wv.y);
    o.z = f2bf(xv.z * inv * wv.z);
    o.w = f2bf(xv.w * inv * wv.w);
    *reinterpret_cast<ushort4*>(&out[(size_t)row * DD + tid * 4]) = o;
}

// ---------------- weight transpose+convert: fp32 [K][N] (or (H,D,HS)) -> bf16 [N][K] ----------------
template<bool HEADW>
__global__ __launch_bounds__(256) void wtrans(const float* __restrict__ W,
                                              unsigned short* __restrict__ Wt,
                                              int K, int N) {
    __shared__ float t[64][65];
    const int k0 = blockIdx.x * 64;
    const int n0 = blockIdx.y * 64;
    const int tid = threadIdx.x;

    #pragma unroll
    for (int r = 0; r < 4; ++r) {
        const int idx = tid + r * 256;       // 0..1023
        const int kl  = idx >> 4;            // 0..63
        const int nl4 = (idx & 15) * 4;
        const float* gp;
        if (HEADW) {  // w[h][k][e], n = h*64+e, tile is one head
            gp = W + ((size_t)(n0 >> 6) * K + (k0 + kl)) * 64 + nl4;
        } else {
            gp = W + (size_t)(k0 + kl) * N + n0 + nl4;
        }
        float4 v = *reinterpret_cast<const float4*>(gp);
        t[kl][nl4 + 0] = v.x; t[kl][nl4 + 1] = v.y;
        t[kl][nl4 + 2] = v.z; t[kl][nl4 + 3] = v.w;
    }
    __syncthreads();
    #pragma unroll
    for (int r = 0; r < 4; ++r) {
        const int idx = tid + r * 256;
        const int nl  = idx >> 4;
        const int kl4 = (idx & 15) * 4;
        ushort4 o;
        o.x = f2bf(t[kl4 + 0][nl]);
        o.y = f2bf(t[kl4 + 1][nl]);
        o.z = f2bf(t[kl4 + 2][nl]);
        o.w = f2bf(t[kl4 + 3][nl]);
        *reinterpret_cast<ushort4*>(&Wt[(size_t)(n0 + nl) * K + k0 + kl4]) = o;
    }
}

__global__ void pack_bias(const float* __restrict__ a, const float* __restrict__ b,
                          const float* __restrict__ c, float* __restrict__ o) {
    const int i = blockIdx.x * 256 + threadIdx.x;
    if (i < 1024) { o[i] = a[i]; o[i + 1024] = b[i]; o[i + 2048] = c[i]; }
}

// ---------------- bf16 MFMA GEMM: C[M,N] = A[M,K] @ Bt[N,K]^T ----------------
// BN=128 fixed, BK=32, 256 threads = 4 waves.
// BM=128: waves 2x2, wave tile 64x64 (4x4 frags). BM=64: waves 1x4, wave tile 64x32.
// EPI: 0 none, 1 +bias, 2 +bias+GELU(exact), 3 +bias+resid
// HEADOUT: n in [0,3072): out idx = mat*2M + ((b*H+h)*T+t)*HS + e
// SPLITA: blocks with n0>=splitN read A2 instead of A1
template<int BM, int EPI, bool HEADOUT, bool SPLITA, bool OBF16, bool OUT2>
__global__ __launch_bounds__(256, 2) void gemm_mfma(
    const unsigned short* __restrict__ A1,
    const unsigned short* __restrict__ A2,
    const unsigned short* __restrict__ Bt,
    const float* __restrict__ bias,
    const float* __restrict__ resid,
    float* __restrict__ outF,
    unsigned short* __restrict__ outH,
    unsigned short* __restrict__ outH2,
    int N, int K, int splitN)
{
    constexpr int BK = 32;
    constexpr int MI = 4;
    constexpr int NI = (BM == 128) ? 4 : 2;
    constexpr int WN = (BM == 128) ? 64 : 32;
    constexpr int ASLOT = BM * 4;          // 16B slots per A tile
    constexpr int AINST = ASLOT / 256;     // global_load_lds per wave for A

    __shared__ unsigned short ldsA[2][ASLOT * 8];
    __shared__ unsigned short ldsB[2][512 * 8];

    const int tid  = threadIdx.x;
    const int lane = tid & 63;
    const int wid  = tid >> 6;
    const int m0 = blockIdx.y * BM;
    const int n0 = blockIdx.x * 128;
    const int wm = (BM == 128) ? (wid >> 1) : 0;
    const int wn = (BM == 128) ? (wid & 1) : wid;

    const unsigned short* Aptr = (SPLITA && n0 >= splitN) ? A2 : A1;

    f32x4 acc[MI][NI];
    #pragma unroll
    for (int i = 0; i < MI; ++i)
        #pragma unroll
        for (int j = 0; j < NI; ++j)
            acc[i][j] = (f32x4){0.f, 0.f, 0.f, 0.f};

    auto stage = [&](int buf, int kt) {
        const int k0 = kt * BK;
        #pragma unroll
        for (int i = 0; i < AINST; ++i) {
            const int s   = (wid * AINST + i) * 64 + lane;   // 0..ASLOT
            const int kh  = s / BM;
            const int row = s % BM;
            load_lds16(Aptr + (size_t)(m0 + row) * K + (k0 + kh * 8),
                       &ldsA[buf][s * 8]);
        }
        #pragma unroll
        for (int i = 0; i < 2; ++i) {
            const int s   = (wid * 2 + i) * 64 + lane;       // 0..512
            const int kh  = s >> 7;
            const int col = s & 127;
            load_lds16(Bt + (size_t)(n0 + col) * K + (k0 + kh * 8),
                       &ldsB[buf][s * 8]);
        }
    };

    const int NT = K / BK;
    stage(0, 0);
    __syncthreads();
    int cur = 0;
    const int l15 = lane & 15, l4 = lane >> 4;
    for (int kt = 0; kt < NT; ++kt) {
        if (kt + 1 < NT) stage(cur ^ 1, kt + 1);
        bf16x8 af[MI], bfr[NI];
        #pragma unroll
        for (int mi = 0; mi < MI; ++mi)
            af[mi] = *reinterpret_cast<const bf16x8*>(
                &ldsA[cur][(l4 * BM + wm * 64 + mi * 16 + l15) * 8]);
        #pragma unroll
        for (int ni = 0; ni < NI; ++ni)
            bfr[ni] = *reinterpret_cast<const bf16x8*>(
                &ldsB[cur][(l4 * 128 + wn * WN + ni * 16 + l15) * 8]);
        #pragma unroll
        for (int mi = 0; mi < MI; ++mi)
            #pragma unroll
            for (int ni = 0; ni < NI; ++ni)
                acc[mi][ni] = __builtin_amdgcn_mfma_f32_16x16x32_bf16(
                    af[mi], bfr[ni], acc[mi][ni], 0, 0, 0);
        __syncthreads();
        cur ^= 1;
    }

    // epilogue: C/D layout col = lane&15, row = (lane>>4)*4 + reg
    #pragma unroll
    for (int mi = 0; mi < MI; ++mi) {
        #pragma unroll
        for (int ni = 0; ni < NI; ++ni) {
            #pragma unroll
            for (int r = 0; r < 4; ++r) {
                const int row = m0 + wm * 64 + mi * 16 + l4 * 4 + r;
                const int col = n0 + wn * WN + ni * 16 + l15;
                float v = acc[mi][ni][r];
                if (EPI >= 1) v += bias[col];
                if (EPI == 2) v = 0.5f * v * (1.0f + erff(v * 0.70710678118f));
                if (EPI == 3) v += resid[(size_t)row * N + col];
                size_t oidx;
                if (HEADOUT) {
                    const int mat = col >> 10;
                    const int h = (col >> 6) & 15, e = col & 63;
                    const int b = row >> 10, t = row & (TT - 1);
                    oidx = (size_t)mat * ((size_t)NROWS * DD)
                         + ((size_t)((b * HH + h) * TT + t)) * HS + e;
                } else {
                    oidx = (size_t)row * N + col;
                }
                if (OBF16) outH[oidx] = f2bf(v);
                else       outF[oidx] = v;
                if (OUT2)  outH2[oidx] = f2bf(v);
            }
        }
    }
}

// ---------------- Tiled flash attention (bf16 in/out, fp32 compute) ----------------
template<bool CAUSAL>
__global__ __launch_bounds__(256) void attn_tile(const unsigned short* __restrict__ Q,
                                                 const unsigned short* __restrict__ Km,
                                                 const unsigned short* __restrict__ Vm,
                                                 unsigned short* __restrict__ O) {
    const int iq  = blockIdx.x;
    const int bh  = blockIdx.y;
    const int tid = threadIdx.x;
    const int tx  = tid & 15;
    const int ty  = tid >> 4;

    __shared__ float Qs[HS][68];   // Q^T (pre-scaled)
    __shared__ float Ks[HS][68];   // K^T
    __shared__ float Vs[64][68];   // V
    __shared__ float Ps[64][68];   // P^T

    const unsigned short* qbase = Q  + ((size_t)bh * TT + (size_t)iq * 64) * HS;
    const unsigned short* kbase = Km + (size_t)bh * TT * HS;
    const unsigned short* vbase = Vm + (size_t)bh * TT * HS;

    #pragma unroll
    for (int r = 0; r < 2; ++r) {
        const int idx = tid + r * 256;   // 0..511
        const int row = idx >> 3;
        const int e0  = (idx & 7) * 8;
        uint4 u = *reinterpret_cast<const uint4*>(qbase + (size_t)row * HS + e0);
        Qs[e0+0][row] = bflo(u.x) * SCALE; Qs[e0+1][row] = bfhi(u.x) * SCALE;
        Qs[e0+2][row] = bflo(u.y) * SCALE; Qs[e0+3][row] = bfhi(u.y) * SCALE;
        Qs[e0+4][row] = bflo(u.z) * SCALE; Qs[e0+5][row] = bfhi(u.z) * SCALE;
        Qs[e0+6][row] = bflo(u.w) * SCALE; Qs[e0+7][row] = bfhi(u.w) * SCALE;
    }

    float o_acc[4][4] = {};
    float m_run[4], l_run[4];
    #pragma unroll
    for (int i = 0; i < 4; ++i) { m_run[i] = -1e30f; l_run[i] = 0.f; }

    const int ntiles = CAUSAL ? (iq + 1) : (TT / 64);
    for (int js = 0; js < ntiles; ++js) {
        __syncthreads();
        #pragma unroll
        for (int r = 0; r < 2; ++r) {
            const int idx = tid + r * 256;
            const int row = idx >> 3;
            const int e0  = (idx & 7) * 8;
            const size_t g = (size_t)(js * 64 + row) * HS + e0;
            uint4 ku = *reinterpret_cast<const uint4*>(kbase + g);
            Ks[e0+0][row] = bflo(ku.x); Ks[e0+1][row] = bfhi(ku.x);
            Ks[e0+2][row] = bflo(ku.y); Ks[e0+3][row] = bfhi(ku.y);
            Ks[e0+4][row] = bflo(ku.z); Ks[e0+5][row] = bfhi(ku.z);
            Ks[e0+6][row] = bflo(ku.w); Ks[e0+7][row] = bfhi(ku.w);
            uint4 vu = *reinterpret_cast<const uint4*>(vbase + g);
            Vs[row][e0+0] = bflo(vu.x); Vs[row][e0+1] = bfhi(vu.x);
            Vs[row][e0+2] = bflo(vu.y); Vs[row][e0+3] = bfhi(vu.y);
            Vs[row][e0+4] = bflo(vu.z); Vs[row][e0+5] = bfhi(vu.z);
            Vs[row][e0+6] = bflo(vu.w); Vs[row][e0+7] = bfhi(vu.w);
        }
        __syncthreads();

        float sacc[4][4] = {};
        #pragma unroll 8
        for (int e = 0; e < HS; ++e) {
            float4 a = *reinterpret_cast<const float4*>(&Qs[e][ty * 4]);
            float4 b = *reinterpret_cast<const float4*>(&Ks[e][tx * 4]);
            float av[4] = {a.x, a.y, a.z, a.w};
            float bv[4] = {b.x, b.y, b.z, b.w};
            #pragma unroll
            for (int i = 0; i < 4; ++i)
                #pragma unroll
                for (int j = 0; j < 4; ++j)
                    sacc[i][j] = fmaf(av[i], bv[j], sacc[i][j]);
        }

        if (CAUSAL && js == iq) {
            #pragma unroll
            for (int i = 0; i < 4; ++i) {
                const int q = ty * 4 + i;
                #pragma unroll
                for (int j = 0; j < 4; ++j)
                    if (tx * 4 + j > q) sacc[i][j] = -1e30f;
            }
        }

        #pragma unroll
        for (int i = 0; i < 4; ++i) {
            float rm = fmaxf(fmaxf(sacc[i][0], sacc[i][1]), fmaxf(sacc[i][2], sacc[i][3]));
            #pragma unroll
            for (int d = 1; d < 16; d <<= 1)
                rm = fmaxf(rm, __shfl_xor(rm, d));
            const float mnew = fmaxf(m_run[i], rm);
            const float corr = __expf(m_run[i] - mnew);
            float sum = 0.f;
            #pragma unroll
            for (int j = 0; j < 4; ++j) {
                const float p = __expf(sacc[i][j] - mnew);
                Ps[tx * 4 + j][ty * 4 + i] = p;
                sum += p;
            }
            #pragma unroll
            for (int d = 1; d < 16; d <<= 1)
                sum += __shfl_xor(sum, d);
            l_run[i] = l_run[i] * corr + sum;
            m_run[i] = mnew;
            #pragma unroll
            for (int j = 0; j < 4; ++j) o_acc[i][j] *= corr;
        }
        __syncthreads();

        #pragma unroll 8
        for (int s = 0; s < 64; ++s) {
            float4 a = *reinterpret_cast<const float4*>(&Ps[s][ty * 4]);
            float4 b = *reinterpret_cast<const float4*>(&Vs[s][tx * 4]);
            float av[4] = {a.x, a.y, a.z, a.w};
            float bv[4] = {b.x, b.y, b.z, b.w};
            #pragma unroll
            for (int i = 0; i < 4; ++i)
                #pragma unroll
                for (int j = 0; j < 4; ++j)
                    o_acc[i][j] = fmaf(av[i], bv[j], o_acc[i][j]);
        }
    }

    const int b = bh >> 4, h = bh & (HH - 1);
    #pragma unroll
    for (int i = 0; i < 4; ++i) {
        const float inv = 1.0f / l_run[i];
        const int t = iq * 64 + ty * 4 + i;
        ushort4 ov;
        ov.x = f2bf(o_acc[i][0] * inv);
        ov.y = f2bf(o_acc[i][1] * inv);
        ov.z = f2bf(o_acc[i][2] * inv);
        ov.w = f2bf(o_acc[i][3] * inv);
        *reinterpret_cast<ushort4*>(&O[((size_t)(b * TT + t)) * DD + h * HS + tx * 4]) = ov;
    }
}

extern "C" void kernel_launch(void* const* d_in, const int* in_sizes, int n_in,
                              void* d_out, int out_size, void* d_ws, size_t ws_size,
                              hipStream_t stream) {
    const float* src      = (const float*)d_in[0];
    const float* att      = (const float*)d_in[1];
    const float* wq_m     = (const float*)d_in[2];
    const float* wk_m     = (const float*)d_in[3];
    const float* wv_m     = (const float*)d_in[4];
    const float* proj_m_w = (const float*)d_in[5];
    const float* proj_m_b = (const float*)d_in[6];
    const float* wq_f     = (const float*)d_in[7];
    const float* wk_f     = (const float*)d_in[8];
    const float* wv_f     = (const float*)d_in[9];
    const float* bq_f     = (const float*)d_in[10];
    const float* bk_f     = (const float*)d_in[11];
    const float* bv_f     = (const float*)d_in[12];
    const float* proj_f_w = (const float*)d_in[13];
    const float* proj_f_b = (const float*)d_in[14];
    const float* w1       = (const float*)d_in[15];
    const float* b1       = (const float*)d_in[16];
    const float* w2       = (const float*)d_in[17];
    const float* b2       = (const float*)d_in[18];
    const float* norm_w   = (const float*)d_in[19];

    const size_t M_ = 1024 * 1024;
    unsigned short* wsb = (unsigned short*)d_ws;
    // bf16 transposed weights (16M ushorts = 32MB)
    unsigned short* wt_qkvm = wsb;                 // [3072][1024]
    unsigned short* wt_projm = wsb + 3 * M_;       // [1024][1024]
    unsigned short* wt_qkvf = wsb + 4 * M_;        // [3072][1024]
    unsigned short* wt_projf = wsb + 7 * M_;       // [1024][1024]
    unsigned short* wt_w1   = wsb + 8 * M_;        // [4096][1024]
    unsigned short* wt_w2   = wsb + 12 * M_;       // [1024][4096]
    // activations
    unsigned short* xn  = wsb + 16 * M_;           // [2048][1024] bf16
    unsigned short* qkv = wsb + 18 * M_;           // q,k,v each 2M ushorts
    unsigned short* ao  = wsb + 24 * M_;           // [2048][1024] bf16
    unsigned short* h1  = wsb + 18 * M_;           // [2048][4096] bf16 (overlays qkv+ao, FFN phase)
    float* m_out = (float*)(wsb + 26 * M_);        // [2048][1024] fp32 (at 52MB)
    // d_out doubles as scratch before its final write:
    unsigned short* mo_bf  = (unsigned short*)d_out;            // [2048][1024] bf16 (4MB)
    float* biascat = (float*)((char*)d_out + 4 * 1024 * 1024);  // 3072 floats
    float* f_out = (float*)d_out;
    float* outp  = (float*)d_out;
    (void)ws_size; (void)in_sizes; (void)n_in;

    const dim3 blk(256);
    const int BIG = 1 << 30;

    // ---- weight prep ----
    pack_bias<<<dim3(4), blk, 0, stream>>>(bq_f, bk_f, bv_f, biascat);
    wtrans<true ><<<dim3(16, 16), blk, 0, stream>>>(wq_m, wt_qkvm + 0 * M_, 1024, 1024);
    wtrans<true ><<<dim3(16, 16), blk, 0, stream>>>(wk_m, wt_qkvm + 1 * M_, 1024, 1024);
    wtrans<true ><<<dim3(16, 16), blk, 0, stream>>>(wv_m, wt_qkvm + 2 * M_, 1024, 1024);
    wtrans<false><<<dim3(16, 16), blk, 0, stream>>>(proj_m_w, wt_projm, 1024, 1024);
    wtrans<true ><<<dim3(16, 16), blk, 0, stream>>>(wq_f, wt_qkvf + 0 * M_, 1024, 1024);
    wtrans<true ><<<dim3(16, 16), blk, 0, stream>>>(wk_f, wt_qkvf + 1 * M_, 1024, 1024);
    wtrans<true ><<<dim3(16, 16), blk, 0, stream>>>(wv_f, wt_qkvf + 2 * M_, 1024, 1024);
    wtrans<false><<<dim3(16, 16), blk, 0, stream>>>(proj_f_w, wt_projf, 1024, 1024);
    wtrans<false><<<dim3(16, 64), blk, 0, stream>>>(w1, wt_w1, 1024, 4096);
    wtrans<false><<<dim3(64, 16), blk, 0, stream>>>(w2, wt_w2, 4096, 1024);

    // ---- masked self-attention block ----
    rmsnorm_kernel<<<dim3(NROWS), blk, 0, stream>>>(src, norm_w, xn);
    gemm_mfma<128, 0, true, false, true, false><<<dim3(24, 16), blk, 0, stream>>>(
        xn, nullptr, wt_qkvm, nullptr, nullptr, nullptr, qkv, nullptr, 3072, 1024, BIG);
    attn_tile<true><<<dim3(16, 32), blk, 0, stream>>>(qkv, qkv + 2 * M_, qkv + 4 * M_, ao);
    gemm_mfma<64, 3, false, false, false, true><<<dim3(8, 32), blk, 0, stream>>>(
        ao, nullptr, wt_projm, proj_m_b, src, m_out, nullptr, mo_bf, 1024, 1024, BIG);

    // ---- cross attention block: q/k from rmsnorm(att), v from m_out ----
    rmsnorm_kernel<<<dim3(NROWS), blk, 0, stream>>>(att, norm_w, xn);
    gemm_mfma<128, 1, true, true, true, false><<<dim3(24, 16), blk, 0, stream>>>(
        xn, mo_bf, wt_qkvf, biascat, nullptr, nullptr, qkv, nullptr, 3072, 1024, 2048);
    attn_tile<false><<<dim3(16, 32), blk, 0, stream>>>(qkv, qkv + 2 * M_, qkv + 4 * M_, ao);
    gemm_mfma<64, 3, false, false, false, false><<<dim3(8, 32), blk, 0, stream>>>(
        ao, nullptr, wt_projf, proj_f_b, m_out, f_out, nullptr, nullptr, 1024, 1024, BIG);

    // ---- FFN block ----
    rmsnorm_kernel<<<dim3(NROWS), blk, 0, stream>>>(f_out, norm_w, xn);
    gemm_mfma<128, 2, false, false, true, false><<<dim3(32, 16), blk, 0, stream>>>(
        xn, nullptr, wt_w1, b1, nullptr, nullptr, h1, nullptr, 4096, 1024, BIG);
    gemm_mfma<64, 3, false, false, false, false><<<dim3(8, 32), blk, 0, stream>>>(
        h1, nullptr, wt_w2, b2, f_out, outp, nullptr, nullptr, 1024, 4096, BIG);
}

// Round 4
// 373.261 us; speedup vs baseline: 12.9227x; 1.5960x over previous
//
#include <hip/hip_runtime.h>
#include <math.h>

#define BB 2
#define TT 1024
#define DD 1024
#define HH 16
#define HS 64
#define NROWS (BB*TT)   // 2048

typedef _Float16 f16;
typedef __attribute__((ext_vector_type(8))) _Float16 half8;
typedef __attribute__((ext_vector_type(4))) _Float16 half4;
typedef __attribute__((ext_vector_type(4))) float f32x4;

constexpr float EPS   = 1e-5f;
constexpr float SCALE = 8.0f;   // faithful bug: scores * sqrt(HS)

__device__ __forceinline__ void load_lds16(const f16* g, f16* l) {
    __builtin_amdgcn_global_load_lds(
        (const __attribute__((address_space(1))) unsigned int*)g,
        (__attribute__((address_space(3))) unsigned int*)l, 16, 0, 0);
}

// ---------------- RMSNorm: fp32 in -> fp16 out ----------------
__global__ __launch_bounds__(256) void rmsnorm_kernel(const float* __restrict__ x,
                                                      const float* __restrict__ w,
                                                      f16* __restrict__ out) {
    const int row = blockIdx.x;
    const int tid = threadIdx.x;
    const float* xr = x + (size_t)row * DD;

    float4 xv = reinterpret_cast<const float4*>(xr)[tid];
    float ss = xv.x*xv.x + xv.y*xv.y + xv.z*xv.z + xv.w*xv.w;

    __shared__ float red[256];
    red[tid] = ss; __syncthreads();
    for (int s = 128; s > 0; s >>= 1) {
        if (tid < s) red[tid] += red[tid + s];
        __syncthreads();
    }
    const float inv = rsqrtf(red[0] * (1.0f / DD) + EPS);

    float4 wv = reinterpret_cast<const float4*>(w)[tid];
    half4 o;
    o.x = (f16)(xv.x * inv * wv.x);
    o.y = (f16)(xv.y * inv * wv.y);
    o.z = (f16)(xv.z * inv * wv.z);
    o.w = (f16)(xv.w * inv * wv.w);
    *reinterpret_cast<half4*>(&out[(size_t)row * DD + tid * 4]) = o;
}

// ---------------- weight transpose+convert: fp32 [K][N] (or (H,D,HS)) -> fp16 [N][K] ----------------
template<bool HEADW>
__global__ __launch_bounds__(256) void wtrans(const float* __restrict__ W,
                                              f16* __restrict__ Wt,
                                              int K, int N) {
    __shared__ float t[64][65];
    const int k0 = blockIdx.x * 64;
    const int n0 = blockIdx.y * 64;
    const int tid = threadIdx.x;

    #pragma unroll
    for (int r = 0; r < 4; ++r) {
        const int idx = tid + r * 256;
        const int kl  = idx >> 4;
        const int nl4 = (idx & 15) * 4;
        const float* gp;
        if (HEADW) {
            gp = W + ((size_t)(n0 >> 6) * K + (k0 + kl)) * 64 + nl4;
        } else {
            gp = W + (size_t)(k0 + kl) * N + n0 + nl4;
        }
        float4 v = *reinterpret_cast<const float4*>(gp);
        t[kl][nl4 + 0] = v.x; t[kl][nl4 + 1] = v.y;
        t[kl][nl4 + 2] = v.z; t[kl][nl4 + 3] = v.w;
    }
    __syncthreads();
    #pragma unroll
    for (int r = 0; r < 4; ++r) {
        const int idx = tid + r * 256;
        const int nl  = idx >> 4;
        const int kl4 = (idx & 15) * 4;
        half4 o;
        o.x = (f16)t[kl4 + 0][nl];
        o.y = (f16)t[kl4 + 1][nl];
        o.z = (f16)t[kl4 + 2][nl];
        o.w = (f16)t[kl4 + 3][nl];
        *reinterpret_cast<half4*>(&Wt[(size_t)(n0 + nl) * K + k0 + kl4]) = o;
    }
}

__global__ void pack_bias(const float* __restrict__ a, const float* __restrict__ b,
                          const float* __restrict__ c, float* __restrict__ o) {
    const int i = blockIdx.x * 256 + threadIdx.x;
    if (i < 1024) { o[i] = a[i]; o[i + 1024] = b[i]; o[i + 2048] = c[i]; }
}

// ---------------- fp16 MFMA GEMM: C[M,N] = A[M,K] @ Bt[N,K]^T ----------------
template<int BM, int EPI, bool HEADOUT, bool SPLITA, bool OHALF, bool OUT2>
__global__ __launch_bounds__(256, 2) void gemm_mfma(
    const f16* __restrict__ A1,
    const f16* __restrict__ A2,
    const f16* __restrict__ Bt,
    const float* __restrict__ bias,
    const float* __restrict__ resid,
    float* __restrict__ outF,
    f16* __restrict__ outH,
    f16* __restrict__ outH2,
    int N, int K, int splitN)
{
    constexpr int BK = 32;
    constexpr int MI = 4;
    constexpr int NI = (BM == 128) ? 4 : 2;
    constexpr int WN = (BM == 128) ? 64 : 32;
    constexpr int ASLOT = BM * 4;
    constexpr int AINST = ASLOT / 256;

    __shared__ f16 ldsA[2][ASLOT * 8];
    __shared__ f16 ldsB[2][512 * 8];

    const int tid  = threadIdx.x;
    const int lane = tid & 63;
    const int wid  = tid >> 6;
    const int m0 = blockIdx.y * BM;
    const int n0 = blockIdx.x * 128;
    const int wm = (BM == 128) ? (wid >> 1) : 0;
    const int wn = (BM == 128) ? (wid & 1) : wid;

    const f16* Aptr = (SPLITA && n0 >= splitN) ? A2 : A1;

    f32x4 acc[MI][NI];
    #pragma unroll
    for (int i = 0; i < MI; ++i)
        #pragma unroll
        for (int j = 0; j < NI; ++j)
            acc[i][j] = (f32x4){0.f, 0.f, 0.f, 0.f};

    auto stage = [&](int buf, int kt) {
        const int k0 = kt * BK;
        #pragma unroll
        for (int i = 0; i < AINST; ++i) {
            const int s   = (wid * AINST + i) * 64 + lane;
            const int kh  = s / BM;
            const int row = s % BM;
            load_lds16(Aptr + (size_t)(m0 + row) * K + (k0 + kh * 8),
                       &ldsA[buf][s * 8]);
        }
        #pragma unroll
        for (int i = 0; i < 2; ++i) {
            const int s   = (wid * 2 + i) * 64 + lane;
            const int kh  = s >> 7;
            const int col = s & 127;
            load_lds16(Bt + (size_t)(n0 + col) * K + (k0 + kh * 8),
                       &ldsB[buf][s * 8]);
        }
    };

    const int NT = K / BK;
    stage(0, 0);
    __syncthreads();
    int cur = 0;
    const int l15 = lane & 15, l4 = lane >> 4;
    for (int kt = 0; kt < NT; ++kt) {
        if (kt + 1 < NT) stage(cur ^ 1, kt + 1);
        half8 af[MI], bfr[NI];
        #pragma unroll
        for (int mi = 0; mi < MI; ++mi)
            af[mi] = *reinterpret_cast<const half8*>(
                &ldsA[cur][(l4 * BM + wm * 64 + mi * 16 + l15) * 8]);
        #pragma unroll
        for (int ni = 0; ni < NI; ++ni)
            bfr[ni] = *reinterpret_cast<const half8*>(
                &ldsB[cur][(l4 * 128 + wn * WN + ni * 16 + l15) * 8]);
        #pragma unroll
        for (int mi = 0; mi < MI; ++mi)
            #pragma unroll
            for (int ni = 0; ni < NI; ++ni)
                acc[mi][ni] = __builtin_amdgcn_mfma_f32_16x16x32_f16(
                    af[mi], bfr[ni], acc[mi][ni], 0, 0, 0);
        __syncthreads();
        cur ^= 1;
    }

    #pragma unroll
    for (int mi = 0; mi < MI; ++mi) {
        #pragma unroll
        for (int ni = 0; ni < NI; ++ni) {
            #pragma unroll
            for (int r = 0; r < 4; ++r) {
                const int row = m0 + wm * 64 + mi * 16 + l4 * 4 + r;
                const int col = n0 + wn * WN + ni * 16 + l15;
                float v = acc[mi][ni][r];
                if (EPI >= 1) v += bias[col];
                if (EPI == 2) v = 0.5f * v * (1.0f + erff(v * 0.70710678118f));
                if (EPI == 3) v += resid[(size_t)row * N + col];
                size_t oidx;
                if (HEADOUT) {
                    const int mat = col >> 10;
                    const int h = (col >> 6) & 15, e = col & 63;
                    const int b = row >> 10, t = row & (TT - 1);
                    oidx = (size_t)mat * ((size_t)NROWS * DD)
                         + ((size_t)((b * HH + h) * TT + t)) * HS + e;
                } else {
                    oidx = (size_t)row * N + col;
                }
                if (OHALF) outH[oidx] = (f16)v;
                else       outF[oidx] = v;
                if (OUT2)  outH2[oidx] = (f16)v;
            }
        }
    }
}

// ---------------- MFMA flash attention (fp16 in/out, fp32 softmax/acc) ----------------
// grid (T/64, B*H), 256 threads = 4 waves; wave w owns q rows [w*16, w*16+16).
// Q,K,V in [B,H,T,HS] fp16; output concat-heads [B,T,D] fp16.
template<bool CAUSAL>
__global__ __launch_bounds__(256) void attn_mfma(const f16* __restrict__ Q,
                                                 const f16* __restrict__ Kg,
                                                 const f16* __restrict__ Vg,
                                                 f16* __restrict__ O) {
    const int iq  = blockIdx.x;
    const int bh  = blockIdx.y;
    const int tid = threadIdx.x;
    const int lane = tid & 63;
    const int w   = tid >> 6;
    const int l15 = lane & 15, l4 = lane >> 4;

    __shared__ f16 Ks[512 * 8];      // slot-major: slot = eh*64 + s, 8 contiguous e
    __shared__ f16 VT[64 * 72];      // VT[e][s], row stride 72 (144B)
    __shared__ f16 Ps[4][16 * 72];   // per-wave P[q'][s], row stride 72

    const f16* qb = Q  + ((size_t)bh * TT + (size_t)iq * 64) * HS;
    const f16* kb = Kg + (size_t)bh * TT * HS;
    const f16* vb = Vg + (size_t)bh * TT * HS;

    // Q fragments in registers (q row = w*16 + l15, e = ks*32 + l4*8 + j)
    half8 qf[2];
    #pragma unroll
    for (int ks = 0; ks < 2; ++ks)
        qf[ks] = *reinterpret_cast<const half8*>(
            qb + (size_t)(w * 16 + l15) * HS + ks * 32 + l4 * 8);

    f32x4 oacc[4];
    #pragma unroll
    for (int ni = 0; ni < 4; ++ni) oacc[ni] = (f32x4){0.f, 0.f, 0.f, 0.f};
    float m_run[4], l_run[4];
    #pragma unroll
    for (int r = 0; r < 4; ++r) { m_run[r] = -1e30f; l_run[r] = 0.f; }

    const int sp  = lane & 31;       // s-pair index for V transpose
    const int ehv = lane >> 5;
    const int c0  = w * 16 + ehv * 8;   // e-chunk this lane transposes

    const int ntiles = CAUSAL ? (iq + 1) : (TT / 64);
    for (int js = 0; js < ntiles; ++js) {
        __syncthreads();   // previous tile fully consumed

        // stage K slot-major via global_load_lds (2 slots/thread)
        #pragma unroll
        for (int i = 0; i < 2; ++i) {
            const int slot = (w * 2 + i) * 64 + lane;
            load_lds16(kb + (size_t)(js * 64 + (slot & 63)) * HS + (slot >> 6) * 8,
                       &Ks[slot * 8]);
        }
        // stage V transposed: lane loads rows 2sp,2sp+1 cols c0..c0+8, writes packed u32
        {
            const f16* vrow = vb + (size_t)(js * 64 + 2 * sp) * HS + c0;
            uint4 r0 = *reinterpret_cast<const uint4*>(vrow);
            uint4 r1 = *reinterpret_cast<const uint4*>(vrow + HS);
            const unsigned rc0[4] = {r0.x, r0.y, r0.z, r0.w};
            const unsigned rc1[4] = {r1.x, r1.y, r1.z, r1.w};
            #pragma unroll
            for (int i = 0; i < 8; ++i) {
                const unsigned lo = (i & 1) ? (rc0[i >> 1] >> 16) : (rc0[i >> 1] & 0xffffu);
                const unsigned hi = (i & 1) ? (rc1[i >> 1] >> 16) : (rc1[i >> 1] & 0xffffu);
                *reinterpret_cast<unsigned*>(&VT[(c0 + i) * 72 + 2 * sp]) = lo | (hi << 16);
            }
        }
        __syncthreads();

        // S = Q . K^T  (m=q 16, n=s 64, k=e 64)
        f32x4 sacc[4];
        #pragma unroll
        for (int ni = 0; ni < 4; ++ni) sacc[ni] = (f32x4){0.f, 0.f, 0.f, 0.f};
        #pragma unroll
        for (int ks = 0; ks < 2; ++ks) {
            #pragma unroll
            for (int ni = 0; ni < 4; ++ni) {
                half8 kf = *reinterpret_cast<const half8*>(
                    &Ks[((ks * 4 + l4) * 64 + ni * 16 + l15) * 8]);
                sacc[ni] = __builtin_amdgcn_mfma_f32_16x16x32_f16(qf[ks], kf, sacc[ni], 0, 0, 0);
            }
        }

        // scale + causal mask (C layout: q' = l4*4+r, s = ni*16+l15)
        float sv[4][4];
        #pragma unroll
        for (int ni = 0; ni < 4; ++ni) {
            #pragma unroll
            for (int r = 0; r < 4; ++r) {
                float x = sacc[ni][r] * SCALE;
                if (CAUSAL && js == iq) {
                    const int sg = js * 64 + ni * 16 + l15;
                    const int qg = iq * 64 + w * 16 + l4 * 4 + r;
                    if (sg > qg) x = -1e30f;
                }
                sv[ni][r] = x;
            }
        }

        // online softmax per q-row (row spread across 16 lanes of same l4)
        #pragma unroll
        for (int r = 0; r < 4; ++r) {
            float rm = fmaxf(fmaxf(sv[0][r], sv[1][r]), fmaxf(sv[2][r], sv[3][r]));
            rm = fmaxf(rm, __shfl_xor(rm, 1));
            rm = fmaxf(rm, __shfl_xor(rm, 2));
            rm = fmaxf(rm, __shfl_xor(rm, 4));
            rm = fmaxf(rm, __shfl_xor(rm, 8));
            const float mnew = fmaxf(m_run[r], rm);
            const float corr = __expf(m_run[r] - mnew);
            float p0 = __expf(sv[0][r] - mnew);
            float p1 = __expf(sv[1][r] - mnew);
            float p2 = __expf(sv[2][r] - mnew);
            float p3 = __expf(sv[3][r] - mnew);
            float sum = p0 + p1 + p2 + p3;
            sum += __shfl_xor(sum, 1);
            sum += __shfl_xor(sum, 2);
            sum += __shfl_xor(sum, 4);
            sum += __shfl_xor(sum, 8);
            l_run[r] = l_run[r] * corr + sum;
            m_run[r] = mnew;
            #pragma unroll
            for (int ni = 0; ni < 4; ++ni) oacc[ni][r] *= corr;
            f16* prow = &Ps[w][(l4 * 4 + r) * 72];
            prow[ 0 + l15] = (f16)p0;
            prow[16 + l15] = (f16)p1;
            prow[32 + l15] = (f16)p2;
            prow[48 + l15] = (f16)p3;
        }

        // O += P . V  (m=q 16, n=e 64, k=s 64); A from Ps rows, B from VT rows
        #pragma unroll
        for (int ks = 0; ks < 2; ++ks) {
            half8 pf = *reinterpret_cast<const half8*>(&Ps[w][l15 * 72 + ks * 32 + l4 * 8]);
            #pragma unroll
            for (int ni = 0; ni < 4; ++ni) {
                half8 vf = *reinterpret_cast<const half8*>(
                    &VT[(ni * 16 + l15) * 72 + ks * 32 + l4 * 8]);
                oacc[ni] = __builtin_amdgcn_mfma_f32_16x16x32_f16(pf, vf, oacc[ni], 0, 0, 0);
            }
        }
    }

    // epilogue: normalize, store fp16 concat-heads [B,T,D]
    const int b = bh >> 4, h = bh & (HH - 1);
    #pragma unroll
    for (int r = 0; r < 4; ++r) {
        const float inv = 1.0f / l_run[r];
        const int t = iq * 64 + w * 16 + l4 * 4 + r;
        #pragma unroll
        for (int ni = 0; ni < 4; ++ni)
            O[((size_t)(b * TT + t)) * DD + h * HS + ni * 16 + l15] =
                (f16)(oacc[ni][r] * inv);
    }
}

extern "C" void kernel_launch(void* const* d_in, const int* in_sizes, int n_in,
                              void* d_out, int out_size, void* d_ws, size_t ws_size,
                              hipStream_t stream) {
    const float* src      = (const float*)d_in[0];
    const float* att      = (const float*)d_in[1];
    const float* wq_m     = (const float*)d_in[2];
    const float* wk_m     = (const float*)d_in[3];
    const float* wv_m     = (const float*)d_in[4];
    const float* proj_m_w = (const float*)d_in[5];
    const float* proj_m_b = (const float*)d_in[6];
    const float* wq_f     = (const float*)d_in[7];
    const float* wk_f     = (const float*)d_in[8];
    const float* wv_f     = (const float*)d_in[9];
    const float* bq_f     = (const float*)d_in[10];
    const float* bk_f     = (const float*)d_in[11];
    const float* bv_f     = (const float*)d_in[12];
    const float* proj_f_w = (const float*)d_in[13];
    const float* proj_f_b = (const float*)d_in[14];
    const float* w1       = (const float*)d_in[15];
    const float* b1       = (const float*)d_in[16];
    const float* w2       = (const float*)d_in[17];
    const float* b2       = (const float*)d_in[18];
    const float* norm_w   = (const float*)d_in[19];

    const size_t M_ = 1024 * 1024;
    f16* wsb = (f16*)d_ws;
    f16* wt_qkvm = wsb;                 // [3072][1024]
    f16* wt_projm = wsb + 3 * M_;       // [1024][1024]
    f16* wt_qkvf = wsb + 4 * M_;        // [3072][1024]
    f16* wt_projf = wsb + 7 * M_;       // [1024][1024]
    f16* wt_w1   = wsb + 8 * M_;        // [4096][1024]
    f16* wt_w2   = wsb + 12 * M_;       // [1024][4096]
    f16* xn  = wsb + 16 * M_;           // [2048][1024]
    f16* qkv = wsb + 18 * M_;           // q,k,v each 2M
    f16* ao  = wsb + 24 * M_;           // [2048][1024]
    f16* h1  = wsb + 18 * M_;           // [2048][4096] (overlays qkv+ao in FFN phase)
    float* m_out = (float*)(wsb + 26 * M_);   // [2048][1024] fp32
    // d_out as scratch before final write:
    f16* mo_h  = (f16*)d_out;                                   // [2048][1024] f16
    float* biascat = (float*)((char*)d_out + 4 * 1024 * 1024);  // 3072 floats
    float* f_out = (float*)d_out;
    float* outp  = (float*)d_out;
    (void)ws_size; (void)in_sizes; (void)n_in;

    const dim3 blk(256);
    const int BIG = 1 << 30;

    // ---- weight prep ----
    pack_bias<<<dim3(4), blk, 0, stream>>>(bq_f, bk_f, bv_f, biascat);
    wtrans<true ><<<dim3(16, 16), blk, 0, stream>>>(wq_m, wt_qkvm + 0 * M_, 1024, 1024);
    wtrans<true ><<<dim3(16, 16), blk, 0, stream>>>(wk_m, wt_qkvm + 1 * M_, 1024, 1024);
    wtrans<true ><<<dim3(16, 16), blk, 0, stream>>>(wv_m, wt_qkvm + 2 * M_, 1024, 1024);
    wtrans<false><<<dim3(16, 16), blk, 0, stream>>>(proj_m_w, wt_projm, 1024, 1024);
    wtrans<true ><<<dim3(16, 16), blk, 0, stream>>>(wq_f, wt_qkvf + 0 * M_, 1024, 1024);
    wtrans<true ><<<dim3(16, 16), blk, 0, stream>>>(wk_f, wt_qkvf + 1 * M_, 1024, 1024);
    wtrans<true ><<<dim3(16, 16), blk, 0, stream>>>(wv_f, wt_qkvf + 2 * M_, 1024, 1024);
    wtrans<false><<<dim3(16, 16), blk, 0, stream>>>(proj_f_w, wt_projf, 1024, 1024);
    wtrans<false><<<dim3(16, 64), blk, 0, stream>>>(w1, wt_w1, 1024, 4096);
    wtrans<false><<<dim3(64, 16), blk, 0, stream>>>(w2, wt_w2, 4096, 1024);

    // ---- masked self-attention block ----
    rmsnorm_kernel<<<dim3(NROWS), blk, 0, stream>>>(src, norm_w, xn);
    gemm_mfma<128, 0, true, false, true, false><<<dim3(24, 16), blk, 0, stream>>>(
        xn, nullptr, wt_qkvm, nullptr, nullptr, nullptr, qkv, nullptr, 3072, 1024, BIG);
    attn_mfma<true><<<dim3(16, 32), blk, 0, stream>>>(qkv, qkv + 2 * M_, qkv + 4 * M_, ao);
    gemm_mfma<64, 3, false, false, false, true><<<dim3(8, 32), blk, 0, stream>>>(
        ao, nullptr, wt_projm, proj_m_b, src, m_out, nullptr, mo_h, 1024, 1024, BIG);

    // ---- cross attention block: q/k from rmsnorm(att), v from m_out ----
    rmsnorm_kernel<<<dim3(NROWS), blk, 0, stream>>>(att, norm_w, xn);
    gemm_mfma<128, 1, true, true, true, false><<<dim3(24, 16), blk, 0, stream>>>(
        xn, mo_h, wt_qkvf, biascat, nullptr, nullptr, qkv, nullptr, 3072, 1024, 2048);
    attn_mfma<false><<<dim3(16, 32), blk, 0, stream>>>(qkv, qkv + 2 * M_, qkv + 4 * M_, ao);
    gemm_mfma<64, 3, false, false, false, false><<<dim3(8, 32), blk, 0, stream>>>(
        ao, nullptr, wt_projf, proj_f_b, m_out, f_out, nullptr, nullptr, 1024, 1024, BIG);

    // ---- FFN block ----
    rmsnorm_kernel<<<dim3(NROWS), blk, 0, stream>>>(f_out, norm_w, xn);
    gemm_mfma<128, 2, false, false, true, false><<<dim3(32, 16), blk, 0, stream>>>(
        xn, nullptr, wt_w1, b1, nullptr, nullptr, h1, nullptr, 4096, 1024, BIG);
    gemm_mfma<64, 3, false, false, false, false><<<dim3(8, 32), blk, 0, stream>>>(
        h1, nullptr, wt_w2, b2, f_out, outp, nullptr, nullptr, 1024, 4096, BIG);
}

// Round 5
// 347.156 us; speedup vs baseline: 13.8944x; 1.0752x over previous
//
#include <hip/hip_runtime.h>
#include <math.h>

#define BB 2
#define TT 1024
#define DD 1024
#define HH 16
#define HS 64
#define NROWS (BB*TT)   // 2048

typedef _Float16 f16;
typedef __attribute__((ext_vector_type(8))) _Float16 half8;
typedef __attribute__((ext_vector_type(4))) _Float16 half4;
typedef __attribute__((ext_vector_type(4))) float f32x4;

constexpr float EPS   = 1e-5f;
constexpr float SCALE = 8.0f;   // faithful bug: scores * sqrt(HS)

__device__ __forceinline__ void load_lds16(const f16* g, f16* l) {
    __builtin_amdgcn_global_load_lds(
        (const __attribute__((address_space(1))) unsigned int*)g,
        (__attribute__((address_space(3))) unsigned int*)l, 16, 0, 0);
}

// XCD-aware bijective swizzle of the linear block id (total % 8 == 0).
__device__ __forceinline__ int xcd_swizzle(int lin, int total) {
    if ((total & 7) == 0) {
        const int chunk = total >> 3;
        lin = (lin & 7) * chunk + (lin >> 3);
    }
    return lin;
}

// ---------------- RMSNorm: fp32 in -> fp16 out ----------------
__global__ __launch_bounds__(256) void rmsnorm_kernel(const float* __restrict__ x,
                                                      const float* __restrict__ w,
                                                      f16* __restrict__ out) {
    const int row = blockIdx.x;
    const int tid = threadIdx.x;
    const float* xr = x + (size_t)row * DD;

    float4 xv = reinterpret_cast<const float4*>(xr)[tid];
    float ss = xv.x*xv.x + xv.y*xv.y + xv.z*xv.z + xv.w*xv.w;

    __shared__ float red[256];
    red[tid] = ss; __syncthreads();
    for (int s = 128; s > 0; s >>= 1) {
        if (tid < s) red[tid] += red[tid + s];
        __syncthreads();
    }
    const float inv = rsqrtf(red[0] * (1.0f / DD) + EPS);

    float4 wv = reinterpret_cast<const float4*>(w)[tid];
    half4 o;
    o.x = (f16)(xv.x * inv * wv.x);
    o.y = (f16)(xv.y * inv * wv.y);
    o.z = (f16)(xv.z * inv * wv.z);
    o.w = (f16)(xv.w * inv * wv.w);
    *reinterpret_cast<half4*>(&out[(size_t)row * DD + tid * 4]) = o;
}

// ---------------- weight transpose+convert: fp32 [K][N] (or (H,D,HS)) -> fp16 [N][K] ----------------
template<bool HEADW>
__global__ __launch_bounds__(256) void wtrans(const float* __restrict__ W,
                                              f16* __restrict__ Wt,
                                              int K, int N) {
    __shared__ float t[64][65];
    const int k0 = blockIdx.x * 64;
    const int n0 = blockIdx.y * 64;
    const int tid = threadIdx.x;

    #pragma unroll
    for (int r = 0; r < 4; ++r) {
        const int idx = tid + r * 256;
        const int kl  = idx >> 4;
        const int nl4 = (idx & 15) * 4;
        const float* gp;
        if (HEADW) {
            gp = W + ((size_t)(n0 >> 6) * K + (k0 + kl)) * 64 + nl4;
        } else {
            gp = W + (size_t)(k0 + kl) * N + n0 + nl4;
        }
        float4 v = *reinterpret_cast<const float4*>(gp);
        t[kl][nl4 + 0] = v.x; t[kl][nl4 + 1] = v.y;
        t[kl][nl4 + 2] = v.z; t[kl][nl4 + 3] = v.w;
    }
    __syncthreads();
    #pragma unroll
    for (int r = 0; r < 4; ++r) {
        const int idx = tid + r * 256;
        const int nl  = idx >> 4;
        const int kl4 = (idx & 15) * 4;
        half4 o;
        o.x = (f16)t[kl4 + 0][nl];
        o.y = (f16)t[kl4 + 1][nl];
        o.z = (f16)t[kl4 + 2][nl];
        o.w = (f16)t[kl4 + 3][nl];
        *reinterpret_cast<half4*>(&Wt[(size_t)(n0 + nl) * K + k0 + kl4]) = o;
    }
}

__global__ void pack_bias(const float* __restrict__ a, const float* __restrict__ b,
                          const float* __restrict__ c, float* __restrict__ o) {
    const int i = blockIdx.x * 256 + threadIdx.x;
    if (i < 1024) { o[i] = a[i]; o[i + 1024] = b[i]; o[i + 2048] = c[i]; }
}

// ---------------- fp16 MFMA GEMM, 128-wide N tiles: C = A @ Bt^T ----------------
template<int BM, int EPI, bool HEADOUT, bool SPLITA, bool OHALF, bool OUT2>
__global__ __launch_bounds__(256, 2) void gemm_mfma(
    const f16* __restrict__ A1,
    const f16* __restrict__ A2,
    const f16* __restrict__ Bt,
    const float* __restrict__ bias,
    const float* __restrict__ resid,
    float* __restrict__ outF,
    f16* __restrict__ outH,
    f16* __restrict__ outH2,
    int N, int K, int splitN)
{
    constexpr int BK = 32;
    constexpr int MI = 4;
    constexpr int NI = (BM == 128) ? 4 : 2;
    constexpr int WN = (BM == 128) ? 64 : 32;
    constexpr int ASLOT = BM * 4;
    constexpr int AINST = ASLOT / 256;

    __shared__ f16 ldsA[2][ASLOT * 8];
    __shared__ f16 ldsB[2][512 * 8];

    const int tid  = threadIdx.x;
    const int lane = tid & 63;
    const int wid  = tid >> 6;
    const int gx = gridDim.x;
    const int lin = xcd_swizzle(blockIdx.y * gx + blockIdx.x, gx * gridDim.y);
    const int m0 = (lin / gx) * BM;
    const int n0 = (lin % gx) * 128;
    const int wm = (BM == 128) ? (wid >> 1) : 0;
    const int wn = (BM == 128) ? (wid & 1) : wid;

    const f16* Aptr = (SPLITA && n0 >= splitN) ? A2 : A1;

    f32x4 acc[MI][NI];
    #pragma unroll
    for (int i = 0; i < MI; ++i)
        #pragma unroll
        for (int j = 0; j < NI; ++j)
            acc[i][j] = (f32x4){0.f, 0.f, 0.f, 0.f};

    auto stage = [&](int buf, int kt) {
        const int k0 = kt * BK;
        #pragma unroll
        for (int i = 0; i < AINST; ++i) {
            const int s   = (wid * AINST + i) * 64 + lane;
            const int kh  = s / BM;
            const int row = s % BM;
            load_lds16(Aptr + (size_t)(m0 + row) * K + (k0 + kh * 8),
                       &ldsA[buf][s * 8]);
        }
        #pragma unroll
        for (int i = 0; i < 2; ++i) {
            const int s   = (wid * 2 + i) * 64 + lane;
            const int kh  = s >> 7;
            const int col = s & 127;
            load_lds16(Bt + (size_t)(n0 + col) * K + (k0 + kh * 8),
                       &ldsB[buf][s * 8]);
        }
    };

    const int NT = K / BK;
    stage(0, 0);
    __syncthreads();
    int cur = 0;
    const int l15 = lane & 15, l4 = lane >> 4;
    for (int kt = 0; kt < NT; ++kt) {
        if (kt + 1 < NT) stage(cur ^ 1, kt + 1);
        half8 af[MI], bfr[NI];
        #pragma unroll
        for (int mi = 0; mi < MI; ++mi)
            af[mi] = *reinterpret_cast<const half8*>(
                &ldsA[cur][(l4 * BM + wm * 64 + mi * 16 + l15) * 8]);
        #pragma unroll
        for (int ni = 0; ni < NI; ++ni)
            bfr[ni] = *reinterpret_cast<const half8*>(
                &ldsB[cur][(l4 * 128 + wn * WN + ni * 16 + l15) * 8]);
        #pragma unroll
        for (int mi = 0; mi < MI; ++mi)
            #pragma unroll
            for (int ni = 0; ni < NI; ++ni)
                acc[mi][ni] = __builtin_amdgcn_mfma_f32_16x16x32_f16(
                    af[mi], bfr[ni], acc[mi][ni], 0, 0, 0);
        __syncthreads();
        cur ^= 1;
    }

    #pragma unroll
    for (int mi = 0; mi < MI; ++mi) {
        #pragma unroll
        for (int ni = 0; ni < NI; ++ni) {
            #pragma unroll
            for (int r = 0; r < 4; ++r) {
                const int row = m0 + wm * 64 + mi * 16 + l4 * 4 + r;
                const int col = n0 + wn * WN + ni * 16 + l15;
                float v = acc[mi][ni][r];
                if (EPI >= 1) v += bias[col];
                if (EPI == 2) v = 0.5f * v * (1.0f + erff(v * 0.70710678118f));
                if (EPI == 3) v += resid[(size_t)row * N + col];
                size_t oidx;
                if (HEADOUT) {
                    const int mat = col >> 10;
                    const int h = (col >> 6) & 15, e = col & 63;
                    const int b = row >> 10, t = row & (TT - 1);
                    oidx = (size_t)mat * ((size_t)NROWS * DD)
                         + ((size_t)((b * HH + h) * TT + t)) * HS + e;
                } else {
                    oidx = (size_t)row * N + col;
                }
                if (OHALF) outH[oidx] = (f16)v;
                else       outF[oidx] = v;
                if (OUT2)  outH2[oidx] = (f16)v;
            }
        }
    }
}

// ---------------- fp16 MFMA GEMM, 64x64 tiles, BK=64 (for N=1024 projections) ----
// 4 waves as 2x2, each wave a 32x32 sub-tile (MI=NI=2). Grid (N/64, M/64) = 512
// blocks -> 2 blocks/CU so staging of one block overlaps MFMA of the other.
template<int EPI, bool OHALF, bool OUT2>
__global__ __launch_bounds__(256, 2) void gemm_mfma64(
    const f16* __restrict__ A,
    const f16* __restrict__ Bt,
    const float* __restrict__ bias,
    const float* __restrict__ resid,
    float* __restrict__ outF,
    f16* __restrict__ outH,
    f16* __restrict__ outH2,
    int N, int K)
{
    constexpr int BK = 64;

    __shared__ f16 ldsA[2][512 * 8];   // slot = kh*64 + row, 8 halfs each
    __shared__ f16 ldsB[2][512 * 8];

    const int tid  = threadIdx.x;
    const int lane = tid & 63;
    const int wid  = tid >> 6;
    const int gx = gridDim.x;
    const int lin = xcd_swizzle(blockIdx.y * gx + blockIdx.x, gx * gridDim.y);
    const int m0 = (lin / gx) * 64;
    const int n0 = (lin % gx) * 64;
    const int wm = wid >> 1, wn = wid & 1;
    const int l15 = lane & 15, l4 = lane >> 4;

    f32x4 acc[2][2];
    #pragma unroll
    for (int i = 0; i < 2; ++i)
        #pragma unroll
        for (int j = 0; j < 2; ++j)
            acc[i][j] = (f32x4){0.f, 0.f, 0.f, 0.f};

    auto stage = [&](int buf, int kt) {
        const int k0 = kt * BK;
        #pragma unroll
        for (int i = 0; i < 2; ++i) {
            const int kh = wid * 2 + i;          // 0..7
            load_lds16(A  + (size_t)(m0 + lane) * K + (k0 + kh * 8),
                       &ldsA[buf][(kh * 64 + lane) * 8]);
            load_lds16(Bt + (size_t)(n0 + lane) * K + (k0 + kh * 8),
                       &ldsB[buf][(kh * 64 + lane) * 8]);
        }
    };

    const int NT = K / BK;
    stage(0, 0);
    __syncthreads();
    int cur = 0;
    for (int kt = 0; kt < NT; ++kt) {
        if (kt + 1 < NT) stage(cur ^ 1, kt + 1);
        #pragma unroll
        for (int ks = 0; ks < 2; ++ks) {
            half8 af[2], bfr[2];
            #pragma unroll
            for (int mi = 0; mi < 2; ++mi)
                af[mi] = *reinterpret_cast<const half8*>(
                    &ldsA[cur][((ks * 4 + l4) * 64 + wm * 32 + mi * 16 + l15) * 8]);
            #pragma unroll
            for (int ni = 0; ni < 2; ++ni)
                bfr[ni] = *reinterpret_cast<const half8*>(
                    &ldsB[cur][((ks * 4 + l4) * 64 + wn * 32 + ni * 16 + l15) * 8]);
            #pragma unroll
            for (int mi = 0; mi < 2; ++mi)
                #pragma unroll
                for (int ni = 0; ni < 2; ++ni)
                    acc[mi][ni] = __builtin_amdgcn_mfma_f32_16x16x32_f16(
                        af[mi], bfr[ni], acc[mi][ni], 0, 0, 0);
        }
        __syncthreads();
        cur ^= 1;
    }

    #pragma unroll
    for (int mi = 0; mi < 2; ++mi) {
        #pragma unroll
        for (int ni = 0; ni < 2; ++ni) {
            #pragma unroll
            for (int r = 0; r < 4; ++r) {
                const int row = m0 + wm * 32 + mi * 16 + l4 * 4 + r;
                const int col = n0 + wn * 32 + ni * 16 + l15;
                float v = acc[mi][ni][r];
                if (EPI >= 1) v += bias[col];
                if (EPI == 2) v = 0.5f * v * (1.0f + erff(v * 0.70710678118f));
                if (EPI == 3) v += resid[(size_t)row * N + col];
                const size_t oidx = (size_t)row * N + col;
                if (OHALF) outH[oidx] = (f16)v;
                else       outF[oidx] = v;
                if (OUT2)  outH2[oidx] = (f16)v;
            }
        }
    }
}

// ---------------- MFMA flash attention (fp16 in/out, fp32 softmax/acc) ----------------
template<bool CAUSAL>
__global__ __launch_bounds__(256) void attn_mfma(const f16* __restrict__ Q,
                                                 const f16* __restrict__ Kg,
                                                 const f16* __restrict__ Vg,
                                                 f16* __restrict__ O) {
    const int iq  = blockIdx.x;
    const int bh  = blockIdx.y;
    const int tid = threadIdx.x;
    const int lane = tid & 63;
    const int w   = tid >> 6;
    const int l15 = lane & 15, l4 = lane >> 4;

    __shared__ f16 Ks[512 * 8];      // slot-major: slot = eh*64 + s
    __shared__ f16 VT[64 * 72];      // VT[e][s], row stride 72
    __shared__ f16 Ps[4][16 * 72];   // per-wave P[q'][s], row stride 72

    const f16* qb = Q  + ((size_t)bh * TT + (size_t)iq * 64) * HS;
    const f16* kb = Kg + (size_t)bh * TT * HS;
    const f16* vb = Vg + (size_t)bh * TT * HS;

    half8 qf[2];
    #pragma unroll
    for (int ks = 0; ks < 2; ++ks)
        qf[ks] = *reinterpret_cast<const half8*>(
            qb + (size_t)(w * 16 + l15) * HS + ks * 32 + l4 * 8);

    f32x4 oacc[4];
    #pragma unroll
    for (int ni = 0; ni < 4; ++ni) oacc[ni] = (f32x4){0.f, 0.f, 0.f, 0.f};
    float m_run[4], l_run[4];
    #pragma unroll
    for (int r = 0; r < 4; ++r) { m_run[r] = -1e30f; l_run[r] = 0.f; }

    const int sp  = lane & 31;
    const int ehv = lane >> 5;
    const int c0  = w * 16 + ehv * 8;

    const int ntiles = CAUSAL ? (iq + 1) : (TT / 64);
    for (int js = 0; js < ntiles; ++js) {
        __syncthreads();

        #pragma unroll
        for (int i = 0; i < 2; ++i) {
            const int slot = (w * 2 + i) * 64 + lane;
            load_lds16(kb + (size_t)(js * 64 + (slot & 63)) * HS + (slot >> 6) * 8,
                       &Ks[slot * 8]);
        }
        {
            const f16* vrow = vb + (size_t)(js * 64 + 2 * sp) * HS + c0;
            uint4 r0 = *reinterpret_cast<const uint4*>(vrow);
            uint4 r1 = *reinterpret_cast<const uint4*>(vrow + HS);
            const unsigned rc0[4] = {r0.x, r0.y, r0.z, r0.w};
            const unsigned rc1[4] = {r1.x, r1.y, r1.z, r1.w};
            #pragma unroll
            for (int i = 0; i < 8; ++i) {
                const unsigned lo = (i & 1) ? (rc0[i >> 1] >> 16) : (rc0[i >> 1] & 0xffffu);
                const unsigned hi = (i & 1) ? (rc1[i >> 1] >> 16) : (rc1[i >> 1] & 0xffffu);
                *reinterpret_cast<unsigned*>(&VT[(c0 + i) * 72 + 2 * sp]) = lo | (hi << 16);
            }
        }
        __syncthreads();

        f32x4 sacc[4];
        #pragma unroll
        for (int ni = 0; ni < 4; ++ni) sacc[ni] = (f32x4){0.f, 0.f, 0.f, 0.f};
        #pragma unroll
        for (int ks = 0; ks < 2; ++ks) {
            #pragma unroll
            for (int ni = 0; ni < 4; ++ni) {
                half8 kf = *reinterpret_cast<const half8*>(
                    &Ks[((ks * 4 + l4) * 64 + ni * 16 + l15) * 8]);
                sacc[ni] = __builtin_amdgcn_mfma_f32_16x16x32_f16(qf[ks], kf, sacc[ni], 0, 0, 0);
            }
        }

        float sv[4][4];
        #pragma unroll
        for (int ni = 0; ni < 4; ++ni) {
            #pragma unroll
            for (int r = 0; r < 4; ++r) {
                float x = sacc[ni][r] * SCALE;
                if (CAUSAL && js == iq) {
                    const int sg = js * 64 + ni * 16 + l15;
                    const int qg = iq * 64 + w * 16 + l4 * 4 + r;
                    if (sg > qg) x = -1e30f;
                }
                sv[ni][r] = x;
            }
        }

        #pragma unroll
        for (int r = 0; r < 4; ++r) {
            float rm = fmaxf(fmaxf(sv[0][r], sv[1][r]), fmaxf(sv[2][r], sv[3][r]));
            rm = fmaxf(rm, __shfl_xor(rm, 1));
            rm = fmaxf(rm, __shfl_xor(rm, 2));
            rm = fmaxf(rm, __shfl_xor(rm, 4));
            rm = fmaxf(rm, __shfl_xor(rm, 8));
            const float mnew = fmaxf(m_run[r], rm);
            const float corr = __expf(m_run[r] - mnew);
            float p0 = __expf(sv[0][r] - mnew);
            float p1 = __expf(sv[1][r] - mnew);
            float p2 = __expf(sv[2][r] - mnew);
            float p3 = __expf(sv[3][r] - mnew);
            float sum = p0 + p1 + p2 + p3;
            sum += __shfl_xor(sum, 1);
            sum += __shfl_xor(sum, 2);
            sum += __shfl_xor(sum, 4);
            sum += __shfl_xor(sum, 8);
            l_run[r] = l_run[r] * corr + sum;
            m_run[r] = mnew;
            #pragma unroll
            for (int ni = 0; ni < 4; ++ni) oacc[ni][r] *= corr;
            f16* prow = &Ps[w][(l4 * 4 + r) * 72];
            prow[ 0 + l15] = (f16)p0;
            prow[16 + l15] = (f16)p1;
            prow[32 + l15] = (f16)p2;
            prow[48 + l15] = (f16)p3;
        }

        #pragma unroll
        for (int ks = 0; ks < 2; ++ks) {
            half8 pf = *reinterpret_cast<const half8*>(&Ps[w][l15 * 72 + ks * 32 + l4 * 8]);
            #pragma unroll
            for (int ni = 0; ni < 4; ++ni) {
                half8 vf = *reinterpret_cast<const half8*>(
                    &VT[(ni * 16 + l15) * 72 + ks * 32 + l4 * 8]);
                oacc[ni] = __builtin_amdgcn_mfma_f32_16x16x32_f16(pf, vf, oacc[ni], 0, 0, 0);
            }
        }
    }

    const int b = bh >> 4, h = bh & (HH - 1);
    #pragma unroll
    for (int r = 0; r < 4; ++r) {
        const float inv = 1.0f / l_run[r];
        const int t = iq * 64 + w * 16 + l4 * 4 + r;
        #pragma unroll
        for (int ni = 0; ni < 4; ++ni)
            O[((size_t)(b * TT + t)) * DD + h * HS + ni * 16 + l15] =
                (f16)(oacc[ni][r] * inv);
    }
}

extern "C" void kernel_launch(void* const* d_in, const int* in_sizes, int n_in,
                              void* d_out, int out_size, void* d_ws, size_t ws_size,
                              hipStream_t stream) {
    const float* src      = (const float*)d_in[0];
    const float* att      = (const float*)d_in[1];
    const float* wq_m     = (const float*)d_in[2];
    const float* wk_m     = (const float*)d_in[3];
    const float* wv_m     = (const float*)d_in[4];
    const float* proj_m_w = (const float*)d_in[5];
    const float* proj_m_b = (const float*)d_in[6];
    const float* wq_f     = (const float*)d_in[7];
    const float* wk_f     = (const float*)d_in[8];
    const float* wv_f     = (const float*)d_in[9];
    const float* bq_f     = (const float*)d_in[10];
    const float* bk_f     = (const float*)d_in[11];
    const float* bv_f     = (const float*)d_in[12];
    const float* proj_f_w = (const float*)d_in[13];
    const float* proj_f_b = (const float*)d_in[14];
    const float* w1       = (const float*)d_in[15];
    const float* b1       = (const float*)d_in[16];
    const float* w2       = (const float*)d_in[17];
    const float* b2       = (const float*)d_in[18];
    const float* norm_w   = (const float*)d_in[19];

    const size_t M_ = 1024 * 1024;
    f16* wsb = (f16*)d_ws;
    f16* wt_qkvm = wsb;                 // [3072][1024]
    f16* wt_projm = wsb + 3 * M_;       // [1024][1024]
    f16* wt_qkvf = wsb + 4 * M_;        // [3072][1024]
    f16* wt_projf = wsb + 7 * M_;       // [1024][1024]
    f16* wt_w1   = wsb + 8 * M_;        // [4096][1024]
    f16* wt_w2   = wsb + 12 * M_;       // [1024][4096]
    f16* xn  = wsb + 16 * M_;           // [2048][1024]
    f16* qkv = wsb + 18 * M_;           // q,k,v each 2M
    f16* ao  = wsb + 24 * M_;           // [2048][1024]
    f16* h1  = wsb + 18 * M_;           // [2048][4096] (overlays qkv+ao in FFN phase)
    float* m_out = (float*)(wsb + 26 * M_);   // [2048][1024] fp32
    f16* mo_h  = (f16*)d_out;                                   // [2048][1024] f16
    float* biascat = (float*)((char*)d_out + 4 * 1024 * 1024);  // 3072 floats
    float* f_out = (float*)d_out;
    float* outp  = (float*)d_out;
    (void)ws_size; (void)in_sizes; (void)n_in;

    const dim3 blk(256);
    const int BIG = 1 << 30;

    // ---- weight prep ----
    pack_bias<<<dim3(4), blk, 0, stream>>>(bq_f, bk_f, bv_f, biascat);
    wtrans<true ><<<dim3(16, 16), blk, 0, stream>>>(wq_m, wt_qkvm + 0 * M_, 1024, 1024);
    wtrans<true ><<<dim3(16, 16), blk, 0, stream>>>(wk_m, wt_qkvm + 1 * M_, 1024, 1024);
    wtrans<true ><<<dim3(16, 16), blk, 0, stream>>>(wv_m, wt_qkvm + 2 * M_, 1024, 1024);
    wtrans<false><<<dim3(16, 16), blk, 0, stream>>>(proj_m_w, wt_projm, 1024, 1024);
    wtrans<true ><<<dim3(16, 16), blk, 0, stream>>>(wq_f, wt_qkvf + 0 * M_, 1024, 1024);
    wtrans<true ><<<dim3(16, 16), blk, 0, stream>>>(wk_f, wt_qkvf + 1 * M_, 1024, 1024);
    wtrans<true ><<<dim3(16, 16), blk, 0, stream>>>(wv_f, wt_qkvf + 2 * M_, 1024, 1024);
    wtrans<false><<<dim3(16, 16), blk, 0, stream>>>(proj_f_w, wt_projf, 1024, 1024);
    wtrans<false><<<dim3(16, 64), blk, 0, stream>>>(w1, wt_w1, 1024, 4096);
    wtrans<false><<<dim3(64, 16), blk, 0, stream>>>(w2, wt_w2, 4096, 1024);

    // ---- masked self-attention block ----
    rmsnorm_kernel<<<dim3(NROWS), blk, 0, stream>>>(src, norm_w, xn);
    gemm_mfma<128, 0, true, false, true, false><<<dim3(24, 16), blk, 0, stream>>>(
        xn, nullptr, wt_qkvm, nullptr, nullptr, nullptr, qkv, nullptr, 3072, 1024, BIG);
    attn_mfma<true><<<dim3(16, 32), blk, 0, stream>>>(qkv, qkv + 2 * M_, qkv + 4 * M_, ao);
    gemm_mfma64<3, false, true><<<dim3(16, 32), blk, 0, stream>>>(
        ao, wt_projm, proj_m_b, src, m_out, nullptr, mo_h, 1024, 1024);

    // ---- cross attention block: q/k from rmsnorm(att), v from m_out ----
    rmsnorm_kernel<<<dim3(NROWS), blk, 0, stream>>>(att, norm_w, xn);
    gemm_mfma<128, 1, true, true, true, false><<<dim3(24, 16), blk, 0, stream>>>(
        xn, mo_h, wt_qkvf, biascat, nullptr, nullptr, qkv, nullptr, 3072, 1024, 2048);
    attn_mfma<false><<<dim3(16, 32), blk, 0, stream>>>(qkv, qkv + 2 * M_, qkv + 4 * M_, ao);
    gemm_mfma64<3, false, false><<<dim3(16, 32), blk, 0, stream>>>(
        ao, wt_projf, proj_f_b, m_out, f_out, nullptr, nullptr, 1024, 1024);

    // ---- FFN block ----
    rmsnorm_kernel<<<dim3(NROWS), blk, 0, stream>>>(f_out, norm_w, xn);
    gemm_mfma<128, 2, false, false, true, false><<<dim3(32, 16), blk, 0, stream>>>(
        xn, nullptr, wt_w1, b1, nullptr, nullptr, h1, nullptr, 4096, 1024, BIG);
    gemm_mfma64<3, false, false><<<dim3(16, 32), blk, 0, stream>>>(
        h1, wt_w2, b2, f_out, outp, nullptr, nullptr, 1024, 4096);
}